// Round 17
// baseline (255.958 us; speedup 1.0000x reference)
//
#include <hip/hip_runtime.h>
#include <stdint.h>

typedef __attribute__((ext_vector_type(8))) short bf16x8;
typedef __attribute__((ext_vector_type(4))) float f32x4;

#define LOG2E 1.4426950408889634f

__device__ __forceinline__ unsigned short f2bf(float f){
  union { float f; unsigned u; } v; v.f = f;
  return (unsigned short)((v.u + 0x7fffu + ((v.u >> 16) & 1u)) >> 16);
}
__device__ __forceinline__ float bf2f(unsigned short h){
  union { unsigned u; float f; } v; v.u = ((unsigned)h) << 16; return v.f;
}
__device__ __forceinline__ float fast_exp2(float x){
  float r; asm("v_exp_f32 %0, %1" : "=v"(r) : "v"(x)); return r;
}
__device__ __forceinline__ unsigned cvt_pk_bf16(float lo, float hi){
  unsigned r; asm("v_cvt_pk_bf16_f32 %0, %1, %2" : "=v"(r) : "v"(lo), "v"(hi)); return r;
}
__device__ __forceinline__ void gload16(const void* g, void* lds){
  __builtin_amdgcn_global_load_lds((const __attribute__((address_space(1))) unsigned int*)g,
                                   (__attribute__((address_space(3))) unsigned int*)lds,
                                   16, 0, 0);
}
#define MFMA(a,b,c) __builtin_amdgcn_mfma_f32_16x16x32_bf16((a),(b),(c),0,0,0)

// B=8, H=W=64, N=4096, C=512, nh=8, hd=64

// Merged prep: x->bf16 + weights + bias tables (pre-scaled by log2(e)).
__global__ __launch_bounds__(256)
void k_prep(const float* __restrict__ x, unsigned short* __restrict__ xb,
            const float* __restrict__ Wq, const float* __restrict__ Wkv,
            const float* __restrict__ Wp,
            const float* t1,const float* t2,const float* t3,const float* t4,
            const float* t5,const float* t6,const float* t7,
            unsigned short* __restrict__ wqkv, unsigned short* __restrict__ wsp,
            float* __restrict__ b64, float* __restrict__ b256){
  int gid = blockIdx.x*256 + threadIdx.x;
  int stride = gridDim.x*256;
  int i8 = gid*8;
  if (i8 < 32768*512){
    float4 a = *(const float4*)(x+i8);
    float4 bb = *(const float4*)(x+i8+4);
    *(ushort4*)(xb+i8)   = make_ushort4(f2bf(a.x), f2bf(a.y), f2bf(a.z), f2bf(a.w));
    *(ushort4*)(xb+i8+4) = make_ushort4(f2bf(bb.x), f2bf(bb.y), f2bf(bb.z), f2bf(bb.w));
  }
  for (int e = gid; e < 1536*512; e += stride){
    int r = e >> 9;
    wqkv[e] = f2bf(r < 512 ? Wq[e] : Wkv[e - 512*512]);
  }
  for (int e = gid; e < 512*512; e += stride)
    wsp[e] = f2bf(Wp[e]);
  for (int e = gid; e < 5*4096; e += stride){
    int hh = e >> 12;
    int q = (e >> 6) & 63, kk = e & 63;
    float v;
    if (hh < 2){
      const float* tb = hh ? t2 : t1;
      int r1=q>>4, i1=(q>>2)&3, c1=q&3;
      int r2=kk>>4, i2=(kk>>2)&3, c2=kk&3;
      v = (i1==i2) ? tb[(r1-r2+3)*7 + (c1-c2+3)] : -1e30f;
    } else {
      const float* tb = (hh==2)?t3:((hh==3)?t4:t5);
      int r1=q>>3, c1=q&7, r2=kk>>3, c2=kk&7;
      v = tb[(r1-r2+7)*15 + (c1-c2+7)];
    }
    b64[e] = v * LOG2E;
  }
  for (int e = gid; e < 2*65536; e += stride){
    int hh = e >> 16; int q = (e >> 8) & 255, kk = e & 255;
    const float* tb = hh ? t7 : t6;
    int r1=q>>4, c1=q&15, r2=kk>>4, c2=kk&15;
    b256[e] = tb[(r1-r2+15)*31 + (c1-c2+15)] * LOG2E;
  }
}

// ---------- GEMM (validated), K=512 for both uses ----------
template<int EPI>
__global__ __launch_bounds__(256, 2)
void k_gemm(const unsigned short* __restrict__ A, const unsigned short* __restrict__ Bw,
            int M,
            unsigned short* __restrict__ oq, unsigned short* __restrict__ ok,
            unsigned short* __restrict__ ovt,
            float* __restrict__ of, const float* __restrict__ bias)
{
  __shared__ unsigned short As[128*64];
  __shared__ unsigned short Bs[128*64];
  const int t = threadIdx.x, l = t & 63, w = t >> 6;
  const int mt = M >> 7;
  const int bm = blockIdx.x % mt, bn = blockIdx.x / mt;
  const int m0 = bm << 7, n0 = bn << 7;
  const int wr = w >> 1, wc = w & 1;
  const int lr = l & 15, lg = l >> 4;
  f32x4 acc[4][4] = {};

  for (int k0 = 0; k0 < 512; k0 += 64){
    #pragma unroll
    for (int i = 0; i < 4; i++){
      int rowb = i*32 + w*8;
      int row  = rowb + (l >> 3);
      int sc   = (((l & 7) ^ (row & 7)) << 3);
      gload16(A  + (size_t)(m0 + row)*512 + k0 + sc, &As[rowb*64]);
      gload16(Bw + (size_t)(n0 + row)*512 + k0 + sc, &Bs[rowb*64]);
    }
    __syncthreads();
    #pragma unroll
    for (int kt = 0; kt < 2; kt++){
      bf16x8 af[4], bfr[4];
      #pragma unroll
      for (int mi = 0; mi < 4; mi++){
        int row = wr*64 + mi*16 + lr;
        int cb  = (kt*64 + lg*16) ^ ((row & 7) << 4);
        af[mi] = *(const bf16x8*)((const char*)As + row*128 + cb);
      }
      #pragma unroll
      for (int ni = 0; ni < 4; ni++){
        int row = wc*64 + ni*16 + lr;
        int cb  = (kt*64 + lg*16) ^ ((row & 7) << 4);
        bfr[ni] = *(const bf16x8*)((const char*)Bs + row*128 + cb);
      }
      #pragma unroll
      for (int mi = 0; mi < 4; mi++)
        #pragma unroll
        for (int ni = 0; ni < 4; ni++)
          acc[mi][ni] = MFMA(af[mi], bfr[ni], acc[mi][ni]);
    }
    __syncthreads();
  }

  #pragma unroll
  for (int mi = 0; mi < 4; mi++){
    #pragma unroll
    for (int ni = 0; ni < 4; ni++){
      int m = m0 + wr*64 + mi*16 + lg*4;
      int o = n0 + wc*64 + ni*16 + lr;
      if (EPI == 0){
        int which = o >> 9, oo = o & 511, h = oo >> 6, d = oo & 63;
        int b_ = m >> 12, n_ = m & 4095;
        if (which == 2){
          *(ushort4*)(ovt + ((((size_t)b_*8 + h)*64 + d) << 12) + n_) =
            make_ushort4(f2bf(acc[mi][ni][0]), f2bf(acc[mi][ni][1]),
                         f2bf(acc[mi][ni][2]), f2bf(acc[mi][ni][3]));
        } else {
          unsigned short* dst = (which == 0) ? oq : ok;
          size_t base = (((size_t)(b_*8 + h)) << 18) + ((size_t)n_ << 6) + d;
          #pragma unroll
          for (int r = 0; r < 4; r++)
            dst[base + (size_t)r*64] = f2bf(acc[mi][ni][r]);
        }
      } else {
        float bv = bias[o];
        #pragma unroll
        for (int r = 0; r < 4; r++)
          of[(size_t)(m + r)*512 + o] = acc[mi][ni][r] + bv;
      }
    }
  }
}

// ---------- unified attention: kg-split P (2KB/wave, 64B rows), pack/PV interleave ----------
// P row layout: 32 cols bf16 (one kg half), row stride 64B, swizzle ((row>>2)&3)<<4.
// Write-set == read-set per row (XOR bits 4-5 keep {0..63}); per-wave DS ordering
// guarantees kg0-reads complete before kg1-overwrites (validated pattern).
__device__ __forceinline__ int map16(int win, int t){
  return (((win >> 2)*16 + (t >> 4)) << 6) + ((win & 3) << 4) + (t & 15);
}
__device__ __forceinline__ int mapw(int h, int u, int t){
  if (h <= 2) return (((u >> 2)*4 + (t >> 4)) << 6) + ((u & 3) << 4) + (t & 15);
  return (((u >> 3)*8 + (t >> 3)) << 6) + ((u & 7) << 3) + (t & 7);
}

__global__ __launch_bounds__(512)
void k_attn(const unsigned short* __restrict__ qb, const unsigned short* __restrict__ kb,
            const unsigned short* __restrict__ vtb,
            const float* __restrict__ b64, const float* __restrict__ b256,
            unsigned short* __restrict__ fsp,
            unsigned short* __restrict__ pO, float* __restrict__ pl)
{
  __shared__ unsigned short KV[2][8192];           // h0/h67: dbuf [K|V]; h15: 2 units
  __shared__ unsigned short Pp[8][1024];           // per-wave P: 32x32 bf16 (kg half)
  const int t = threadIdx.x, l = t & 63, w = t >> 6;
  const int lr = l & 15, lg = l >> 4;
  const int v = (blockIdx.x & 7)*320 + (blockIdx.x >> 3);   // XCD-pinned, 2560 blocks
  const int b = v / 320, u = v % 320;
  const float SC = 0.125f * LOG2E;
  char* pw = (char*)Pp[w];
  bf16x8 ones8;
  #pragma unroll
  for (int e = 0; e < 8; e++) ones8[e] = (short)0x3F80;

  if (u < 160){
    // ================= h0 (KV-chunked) and h6/7 =================
    int h, win, s0, s1, chunk = 0;
    const float* btab = nullptr;
    if (u < 128){ h = 0; win = u >> 3; chunk = u & 7; s0 = chunk*8; s1 = s0 + 8; }
    else { int uu = u - 128; h = 6 + (uu >> 4); win = uu & 15; s0 = 0; s1 = 4;
           btab = b256 + ((size_t)(h - 6) << 16); }
    const size_t hb = ((size_t)(b*8 + h)) << 18;

    const int srow = w*8 + (l >> 3);
    const int ssc  = (((l & 7) ^ (srow & 7)) << 3);

    bf16x8 qf[2][2];
    #pragma unroll
    for (int mf = 0; mf < 2; mf++){
      int qt = w*32 + mf*16 + lr;
      int n = (h == 0) ? (win*256 + qt) : map16(win, qt);
      const unsigned short* qp = qb + hb + ((size_t)n << 6) + lg*8;
      qf[mf][0] = *(const bf16x8*)qp;
      qf[mf][1] = *(const bf16x8*)(qp + 32);
    }
    f32x4 ao[2][4] = {};
    f32x4 lsum4[2] = {};

    auto stage = [&](int s, int buf){
      int tk = s*64 + srow;
      int nk = (h == 0) ? tk : map16(win, tk);
      gload16(kb + hb + ((size_t)nk << 6) + ssc, &KV[buf][w*512]);
      int tv = s*64 + ssc;
      int nv = (h == 0) ? tv : map16(win, tv);
      gload16(vtb + hb + ((size_t)srow << 12) + nv, &KV[buf][4096 + w*512]);
    };

    stage(s0, 0);
    asm volatile("s_waitcnt vmcnt(0)" ::: "memory");
    __builtin_amdgcn_s_barrier();

    const int paswz = ((lr >> 2) & 3) << 4;        // pa-read swizzle (row = mf*16+lr)

    for (int s = s0; s < s1; s++){
      const int cur = (s - s0) & 1;
      if (s + 1 < s1) stage(s + 1, cur ^ 1);
      const char* kpc = (const char*)&KV[cur][0];
      const char* vpc = (const char*)&KV[cur][4096];

      // QK^T (all nf)
      f32x4 sv[2][4] = {};
      __builtin_amdgcn_s_setprio(1);
      #pragma unroll
      for (int kt = 0; kt < 2; kt++){
        bf16x8 kf[4];
        #pragma unroll
        for (int nf = 0; nf < 4; nf++){
          int row = nf*16 + lr;
          int cb  = (kt*64 + lg*16) ^ ((row & 7) << 4);
          kf[nf] = *(const bf16x8*)(kpc + row*128 + cb);
        }
        #pragma unroll
        for (int mf = 0; mf < 2; mf++)
          #pragma unroll
          for (int nf = 0; nf < 4; nf++)
            sv[mf][nf] = MFMA(qf[mf][kt], kf[nf], sv[mf][nf]);
      }
      __builtin_amdgcn_s_setprio(0);

      // per-kg: pack half -> PV half (P buffer reused across kg, wave-private)
      #pragma unroll
      for (int kg = 0; kg < 2; kg++){
        int nfA = kg*2, nfB = kg*2 + 1;
        #pragma unroll
        for (int mf = 0; mf < 2; mf++)
          #pragma unroll
          for (int r = 0; r < 4; r++){
            float xa, xb_;
            if (btab){
              int qw = w*32 + mf*16 + lg*4 + r;
              xa = __builtin_fmaf(sv[mf][nfA][r], SC, btab[(qw << 8) + s*64 + nfA*16 + lr]);
              xb_= __builtin_fmaf(sv[mf][nfB][r], SC, btab[(qw << 8) + s*64 + nfB*16 + lr]);
            } else {
              xa = sv[mf][nfA][r] * SC;
              xb_= sv[mf][nfB][r] * SC;
            }
            unsigned pk = cvt_pk_bf16(fast_exp2(xa), fast_exp2(xb_));
            int row = mf*16 + lg*4 + r;
            int swz = lg << 4;                      // ((row>>2)&3)<<4 == lg<<4
            *(unsigned short*)(pw + row*64 + ((lr*2) ^ swz))        = (unsigned short)pk;
            *(unsigned short*)(pw + row*64 + (((16 + lr)*2) ^ swz)) = (unsigned short)(pk >> 16);
          }
        bf16x8 pa[2], vf[4];
        #pragma unroll
        for (int mf = 0; mf < 2; mf++)
          pa[mf] = *(const bf16x8*)(pw + (mf*16 + lr)*64 + ((lg*16) ^ paswz));
        #pragma unroll
        for (int df = 0; df < 4; df++){
          int row = df*16 + lr;
          int cb  = (kg*64 + lg*16) ^ ((row & 7) << 4);
          vf[df] = *(const bf16x8*)(vpc + row*128 + cb);
        }
        __builtin_amdgcn_s_setprio(1);
        #pragma unroll
        for (int mf = 0; mf < 2; mf++){
          #pragma unroll
          for (int df = 0; df < 4; df++)
            ao[mf][df] = MFMA(pa[mf], vf[df], ao[mf][df]);
          lsum4[mf] = MFMA(pa[mf], ones8, lsum4[mf]);
        }
        __builtin_amdgcn_s_setprio(0);
      }
      asm volatile("s_waitcnt vmcnt(0)" ::: "memory");
      __builtin_amdgcn_s_barrier();
    }

    if (h == 0){
      #pragma unroll
      for (int mf = 0; mf < 2; mf++)
        #pragma unroll
        for (int r = 0; r < 4; r++){
          int qt = w*32 + mf*16 + lg*4 + r;
          size_t rowb = (((size_t)(b*8 + chunk)) << 12) + win*256 + qt;
          if (lr == 0) pl[rowb] = lsum4[mf][r];
          #pragma unroll
          for (int df = 0; df < 4; df++)
            pO[(rowb << 6) + df*16 + lr] = f2bf(ao[mf][df][r]);
        }
    } else {
      #pragma unroll
      for (int mf = 0; mf < 2; mf++)
        #pragma unroll
        for (int df = 0; df < 4; df++)
          #pragma unroll
          for (int r = 0; r < 4; r++){
            float o = ao[mf][df][r] / lsum4[mf][r];
            int qt = w*32 + mf*16 + lg*4 + r;
            int np = win*256 + qt;
            fsp[(((size_t)b*4096 + np) << 9) + h*64 + df*16 + lr] = f2bf(o);
          }
    }
  } else {
    // ================= h1..5: 2 window-units per block, 1 step, mf=1 =================
    int j = u - 160;
    int h = 1 + (j >> 5);
    int jj = j & 31;
    int ui = w >> 2, wi = w & 3;
    int u15 = jj*2 + ui;
    const size_t hb = ((size_t)(b*8 + h)) << 18;
    const float* bt = b64 + ((size_t)(h-1) << 12);
    char* base = (char*)&KV[0][0] + ui*16384;

    #pragma unroll
    for (int i = 0; i < 2; i++){
      int r = wi*16 + i*8 + (l >> 3);
      int sc = (((l & 7) ^ (r & 7)) << 3);
      gload16(kb  + hb + ((size_t)mapw(h, u15, r) << 6) + sc, base + (wi*16 + i*8)*128);
      gload16(vtb + hb + ((size_t)r << 12) + mapw(h, u15, sc), base + 8192 + (wi*16 + i*8)*128);
    }
    bf16x8 qf0, qf1;
    {
      int qt0 = wi*16 + lr;
      int nq = mapw(h, u15, qt0);
      const unsigned short* qp = qb + hb + ((size_t)nq << 6) + lg*8;
      qf0 = *(const bf16x8*)qp;
      qf1 = *(const bf16x8*)(qp + 32);
    }
    asm volatile("s_waitcnt vmcnt(0)" ::: "memory");
    __builtin_amdgcn_s_barrier();

    const char* kpc = base;
    const char* vpc = base + 8192;
    f32x4 ao4[4] = {};
    f32x4 ls = {};
    const int paswz = ((lr >> 2) & 3) << 4;

    #pragma unroll
    for (int kg = 0; kg < 2; kg++){
      f32x4 sv[2] = {};
      __builtin_amdgcn_s_setprio(1);
      #pragma unroll
      for (int kt = 0; kt < 2; kt++)
        #pragma unroll
        for (int nfi = 0; nfi < 2; nfi++){
          int row = (kg*2 + nfi)*16 + lr;
          int cb  = (kt*64 + lg*16) ^ ((row & 7) << 4);
          bf16x8 kf = *(const bf16x8*)(kpc + row*128 + cb);
          sv[nfi] = MFMA(kt == 0 ? qf0 : qf1, kf, sv[nfi]);
        }
      __builtin_amdgcn_s_setprio(0);
      #pragma unroll
      for (int r = 0; r < 4; r++){
        int qw = wi*16 + lg*4 + r;
        float xa = __builtin_fmaf(sv[0][r], SC, bt[(qw << 6) + (kg*2)*16 + lr]);
        float xb_= __builtin_fmaf(sv[1][r], SC, bt[(qw << 6) + (kg*2+1)*16 + lr]);
        unsigned pk = cvt_pk_bf16(fast_exp2(xa), fast_exp2(xb_));
        int row = lg*4 + r;
        int swz = lg << 4;
        *(unsigned short*)(pw + row*64 + ((lr*2) ^ swz))        = (unsigned short)pk;
        *(unsigned short*)(pw + row*64 + (((16 + lr)*2) ^ swz)) = (unsigned short)(pk >> 16);
      }
      bf16x8 pa = *(const bf16x8*)(pw + lr*64 + ((lg*16) ^ paswz));
      __builtin_amdgcn_s_setprio(1);
      #pragma unroll
      for (int df = 0; df < 4; df++){
        int row = df*16 + lr;
        int cb  = (kg*64 + lg*16) ^ ((row & 7) << 4);
        bf16x8 vf = *(const bf16x8*)(vpc + row*128 + cb);
        ao4[df] = MFMA(pa, vf, ao4[df]);
      }
      ls = MFMA(pa, ones8, ls);
      __builtin_amdgcn_s_setprio(0);
    }
    #pragma unroll
    for (int df = 0; df < 4; df++)
      #pragma unroll
      for (int r = 0; r < 4; r++){
        float o = ao4[df][r] / ls[r];
        int qt = wi*16 + lg*4 + r;
        int np;
        if (h <= 2){
          int r4 = qt >> 4, w_ = (qt >> 2) & 3, c = qt & 3;
          np = (u15 >> 2)*256 + (u15 & 3)*64 + w_*16 + r4*4 + c;
        } else {
          np = u15*64 + qt;
        }
        fsp[(((size_t)b*4096 + np) << 9) + h*64 + df*16 + lr] = f2bf(o);
      }
  }
}

// ---------- combine head-0 KV chunks (plain sums) ----------
__global__ __launch_bounds__(256)
void k_comb(const unsigned short* __restrict__ pO, const float* __restrict__ pl,
            unsigned short* __restrict__ fsp){
  int tid = blockIdx.x*256 + threadIdx.x;
  int d = tid & 63;
  int row = tid >> 6;
  int b = row >> 12;
  int n = row & 4095;
  float o = 0.f, L = 0.f;
  #pragma unroll
  for (int c = 0; c < 8; c++){
    size_t rr = (((size_t)(b*8 + c)) << 12) + n;
    L += pl[rr];
    o += bf2f(pO[(rr << 6) + d]);
  }
  o /= L;
  fsp[(((size_t)b*4096 + n) << 9) + d] = f2bf(o);
}

// ---------- launch ----------
extern "C" void kernel_launch(void* const* d_in, const int* in_sizes, int n_in,
                              void* d_out, int out_size, void* d_ws, size_t ws_size,
                              hipStream_t stream) {
  const float* x     = (const float*)d_in[0];
  const float* Wq    = (const float*)d_in[1];
  const float* Wkv   = (const float*)d_in[2];
  const float* Wp    = (const float*)d_in[3];
  const float* bproj = (const float*)d_in[4];
  const float* t1 = (const float*)d_in[7];
  const float* t2 = (const float*)d_in[8];
  const float* t3 = (const float*)d_in[9];
  const float* t4 = (const float*)d_in[10];
  const float* t5 = (const float*)d_in[11];
  const float* t6 = (const float*)d_in[12];
  const float* t7 = (const float*)d_in[13];

  char* W = (char*)d_ws;
  size_t off = 0;
  auto alloc = [&](size_t bytes)->char*{
    char* p = W + off; off += (bytes + 255) & ~(size_t)255; return p;
  };
  unsigned short* xb   = (unsigned short*)alloc((size_t)32768*512*2);   // dead after gemm0
  unsigned short* wqkv = (unsigned short*)alloc((size_t)1536*512*2);    // dead after gemm0
  unsigned short* wsp  = (unsigned short*)alloc((size_t)512*512*2);
  unsigned short* qbuf = (unsigned short*)alloc((size_t)8*8*4096*64*2);
  unsigned short* kbuf = (unsigned short*)alloc((size_t)8*8*4096*64*2);
  unsigned short* vtb  = (unsigned short*)alloc((size_t)8*8*4096*64*2);
  unsigned short* fsp  = (unsigned short*)alloc((size_t)32768*512*2);
  float* b64  = (float*)alloc((size_t)5*64*64*4);
  float* b256 = (float*)alloc((size_t)2*256*256*4);
  if (off > ws_size) return;

  unsigned short* pO = xb;                 // 64 chunk-units * 4096 rows * 64 d * 2B = 32 MiB
  float* pl = (float*)wqkv;                // 64*4096*4B = 1 MiB

  k_prep<<<8192, 256, 0, stream>>>(x, xb, Wq, Wkv, Wp, t1,t2,t3,t4,t5,t6,t7,
                                   wqkv, wsp, b64, b256);
  k_gemm<0><<<3072, 256, 0, stream>>>(xb, wqkv, 32768,
                                      qbuf, kbuf, vtb, nullptr, nullptr);
  k_attn<<<2560, 512, 0, stream>>>(qbuf, kbuf, vtb, b64, b256, fsp, pO, pl);
  k_comb<<<8192, 256, 0, stream>>>(pO, pl, fsp);
  k_gemm<1><<<1024, 256, 0, stream>>>(fsp, wsp, 32768,
                                      nullptr, nullptr, nullptr, (float*)d_out, bproj);
}

// Round 18
// 249.979 us; speedup vs baseline: 1.0239x; 1.0239x over previous
//
#include <hip/hip_runtime.h>
#include <stdint.h>

typedef __attribute__((ext_vector_type(8))) short bf16x8;
typedef __attribute__((ext_vector_type(4))) float f32x4;

#define LOG2E 1.4426950408889634f

__device__ __forceinline__ unsigned short f2bf(float f){
  union { float f; unsigned u; } v; v.f = f;
  return (unsigned short)((v.u + 0x7fffu + ((v.u >> 16) & 1u)) >> 16);
}
__device__ __forceinline__ float bf2f(unsigned short h){
  union { unsigned u; float f; } v; v.u = ((unsigned)h) << 16; return v.f;
}
__device__ __forceinline__ float fast_exp2(float x){
  float r; asm("v_exp_f32 %0, %1" : "=v"(r) : "v"(x)); return r;
}
__device__ __forceinline__ unsigned cvt_pk_bf16(float lo, float hi){
  unsigned r; asm("v_cvt_pk_bf16_f32 %0, %1, %2" : "=v"(r) : "v"(lo), "v"(hi)); return r;
}
__device__ __forceinline__ void gload16(const void* g, void* lds){
  __builtin_amdgcn_global_load_lds((const __attribute__((address_space(1))) unsigned int*)g,
                                   (__attribute__((address_space(3))) unsigned int*)lds,
                                   16, 0, 0);
}
#define MFMA(a,b,c) __builtin_amdgcn_mfma_f32_16x16x32_bf16((a),(b),(c),0,0,0)

// B=8, H=W=64, N=4096, C=512, nh=8, hd=64

// Merged prep: x->bf16 + weights + bias tables (pre-scaled by log2(e)).
__global__ __launch_bounds__(256)
void k_prep(const float* __restrict__ x, unsigned short* __restrict__ xb,
            const float* __restrict__ Wq, const float* __restrict__ Wkv,
            const float* __restrict__ Wp,
            const float* t1,const float* t2,const float* t3,const float* t4,
            const float* t5,const float* t6,const float* t7,
            unsigned short* __restrict__ wqkv, unsigned short* __restrict__ wsp,
            float* __restrict__ b64, float* __restrict__ b256){
  int gid = blockIdx.x*256 + threadIdx.x;
  int stride = gridDim.x*256;
  int i8 = gid*8;
  if (i8 < 32768*512){
    float4 a = *(const float4*)(x+i8);
    float4 bb = *(const float4*)(x+i8+4);
    *(ushort4*)(xb+i8)   = make_ushort4(f2bf(a.x), f2bf(a.y), f2bf(a.z), f2bf(a.w));
    *(ushort4*)(xb+i8+4) = make_ushort4(f2bf(bb.x), f2bf(bb.y), f2bf(bb.z), f2bf(bb.w));
  }
  for (int e = gid; e < 1536*512; e += stride){
    int r = e >> 9;
    wqkv[e] = f2bf(r < 512 ? Wq[e] : Wkv[e - 512*512]);
  }
  for (int e = gid; e < 512*512; e += stride)
    wsp[e] = f2bf(Wp[e]);
  for (int e = gid; e < 5*4096; e += stride){
    int hh = e >> 12;
    int q = (e >> 6) & 63, kk = e & 63;
    float v;
    if (hh < 2){
      const float* tb = hh ? t2 : t1;
      int r1=q>>4, i1=(q>>2)&3, c1=q&3;
      int r2=kk>>4, i2=(kk>>2)&3, c2=kk&3;
      v = (i1==i2) ? tb[(r1-r2+3)*7 + (c1-c2+3)] : -1e30f;
    } else {
      const float* tb = (hh==2)?t3:((hh==3)?t4:t5);
      int r1=q>>3, c1=q&7, r2=kk>>3, c2=kk&7;
      v = tb[(r1-r2+7)*15 + (c1-c2+7)];
    }
    b64[e] = v * LOG2E;
  }
  for (int e = gid; e < 2*65536; e += stride){
    int hh = e >> 16; int q = (e >> 8) & 255, kk = e & 255;
    const float* tb = hh ? t7 : t6;
    int r1=q>>4, c1=q&15, r2=kk>>4, c2=kk&15;
    b256[e] = tb[(r1-r2+15)*31 + (c1-c2+15)] * LOG2E;
  }
}

// ---------- GEMM (validated), K=512 for both uses ----------
template<int EPI>
__global__ __launch_bounds__(256, 2)
void k_gemm(const unsigned short* __restrict__ A, const unsigned short* __restrict__ Bw,
            int M,
            unsigned short* __restrict__ oq, unsigned short* __restrict__ ok,
            unsigned short* __restrict__ ovt,
            float* __restrict__ of, const float* __restrict__ bias)
{
  __shared__ unsigned short As[128*64];
  __shared__ unsigned short Bs[128*64];
  const int t = threadIdx.x, l = t & 63, w = t >> 6;
  const int mt = M >> 7;
  const int bm = blockIdx.x % mt, bn = blockIdx.x / mt;
  const int m0 = bm << 7, n0 = bn << 7;
  const int wr = w >> 1, wc = w & 1;
  const int lr = l & 15, lg = l >> 4;
  f32x4 acc[4][4] = {};

  for (int k0 = 0; k0 < 512; k0 += 64){
    #pragma unroll
    for (int i = 0; i < 4; i++){
      int rowb = i*32 + w*8;
      int row  = rowb + (l >> 3);
      int sc   = (((l & 7) ^ (row & 7)) << 3);
      gload16(A  + (size_t)(m0 + row)*512 + k0 + sc, &As[rowb*64]);
      gload16(Bw + (size_t)(n0 + row)*512 + k0 + sc, &Bs[rowb*64]);
    }
    __syncthreads();
    #pragma unroll
    for (int kt = 0; kt < 2; kt++){
      bf16x8 af[4], bfr[4];
      #pragma unroll
      for (int mi = 0; mi < 4; mi++){
        int row = wr*64 + mi*16 + lr;
        int cb  = (kt*64 + lg*16) ^ ((row & 7) << 4);
        af[mi] = *(const bf16x8*)((const char*)As + row*128 + cb);
      }
      #pragma unroll
      for (int ni = 0; ni < 4; ni++){
        int row = wc*64 + ni*16 + lr;
        int cb  = (kt*64 + lg*16) ^ ((row & 7) << 4);
        bfr[ni] = *(const bf16x8*)((const char*)Bs + row*128 + cb);
      }
      #pragma unroll
      for (int mi = 0; mi < 4; mi++)
        #pragma unroll
        for (int ni = 0; ni < 4; ni++)
          acc[mi][ni] = MFMA(af[mi], bfr[ni], acc[mi][ni]);
    }
    __syncthreads();
  }

  #pragma unroll
  for (int mi = 0; mi < 4; mi++){
    #pragma unroll
    for (int ni = 0; ni < 4; ni++){
      int m = m0 + wr*64 + mi*16 + lg*4;
      int o = n0 + wc*64 + ni*16 + lr;
      if (EPI == 0){
        int which = o >> 9, oo = o & 511, h = oo >> 6, d = oo & 63;
        int b_ = m >> 12, n_ = m & 4095;
        if (which == 2){
          *(ushort4*)(ovt + ((((size_t)b_*8 + h)*64 + d) << 12) + n_) =
            make_ushort4(f2bf(acc[mi][ni][0]), f2bf(acc[mi][ni][1]),
                         f2bf(acc[mi][ni][2]), f2bf(acc[mi][ni][3]));
        } else {
          unsigned short* dst = (which == 0) ? oq : ok;
          size_t base = (((size_t)(b_*8 + h)) << 18) + ((size_t)n_ << 6) + d;
          #pragma unroll
          for (int r = 0; r < 4; r++)
            dst[base + (size_t)r*64] = f2bf(acc[mi][ni][r]);
        }
      } else {
        float bv = bias[o];
        #pragma unroll
        for (int r = 0; r < 4; r++)
          of[(size_t)(m + r)*512 + o] = acc[mi][ni][r] + bv;
      }
    }
  }
}

// ---------- unified attention: R16 P machinery + setprio, h0 4-chunk split ----------
__device__ __forceinline__ int map16(int win, int t){
  return (((win >> 2)*16 + (t >> 4)) << 6) + ((win & 3) << 4) + (t & 15);
}
__device__ __forceinline__ int mapw(int h, int u, int t){
  if (h <= 2) return (((u >> 2)*4 + (t >> 4)) << 6) + ((u & 3) << 4) + (t & 15);
  return (((u >> 3)*8 + (t >> 3)) << 6) + ((u & 7) << 3) + (t & 7);
}

__global__ __launch_bounds__(512)
void k_attn(const unsigned short* __restrict__ qb, const unsigned short* __restrict__ kb,
            const unsigned short* __restrict__ vtb,
            const float* __restrict__ b64, const float* __restrict__ b256,
            unsigned short* __restrict__ fsp,
            unsigned short* __restrict__ pO, float* __restrict__ pl)
{
  __shared__ unsigned short KV[2][8192];           // h0/h67: dbuf [K|V]; h15: 2 units
  __shared__ unsigned short Pp[8][2048];           // per-wave P: 32x64 bf16 (R16 layout)
  const int t = threadIdx.x, l = t & 63, w = t >> 6;
  const int lr = l & 15, lg = l >> 4;
  const int v = (blockIdx.x & 7)*256 + (blockIdx.x >> 3);   // XCD-pinned, 2048 blocks
  const int b = v / 256, u = v % 256;
  const float SC = 0.125f * LOG2E;
  char* pw = (char*)Pp[w];
  bf16x8 ones8;
  #pragma unroll
  for (int e = 0; e < 8; e++) ones8[e] = (short)0x3F80;

  if (u < 96){
    // ================= h0 (4-way KV-chunked) and h6/7 =================
    int h, win, s0, s1, chunk = 0;
    const float* btab = nullptr;
    if (u < 64){ h = 0; win = u >> 2; chunk = u & 3; s0 = chunk*16; s1 = s0 + 16; }
    else { int uu = u - 64; h = 6 + (uu >> 4); win = uu & 15; s0 = 0; s1 = 4;
           btab = b256 + ((size_t)(h - 6) << 16); }
    const size_t hb = ((size_t)(b*8 + h)) << 18;

    const int srow = w*8 + (l >> 3);
    const int ssc  = (((l & 7) ^ (srow & 7)) << 3);

    bf16x8 qf[2][2];
    #pragma unroll
    for (int mf = 0; mf < 2; mf++){
      int qt = w*32 + mf*16 + lr;
      int n = (h == 0) ? (win*256 + qt) : map16(win, qt);
      const unsigned short* qp = qb + hb + ((size_t)n << 6) + lg*8;
      qf[mf][0] = *(const bf16x8*)qp;
      qf[mf][1] = *(const bf16x8*)(qp + 32);
    }
    f32x4 ao[2][4] = {};
    f32x4 lsum4[2] = {};

    auto stage = [&](int s, int buf){
      int tk = s*64 + srow;
      int nk = (h == 0) ? tk : map16(win, tk);
      gload16(kb + hb + ((size_t)nk << 6) + ssc, &KV[buf][w*512]);
      int tv = s*64 + ssc;
      int nv = (h == 0) ? tv : map16(win, tv);
      gload16(vtb + hb + ((size_t)srow << 12) + nv, &KV[buf][4096 + w*512]);
    };

    stage(s0, 0);
    asm volatile("s_waitcnt vmcnt(0)" ::: "memory");
    __builtin_amdgcn_s_barrier();

    for (int s = s0; s < s1; s++){
      const int cur = (s - s0) & 1;
      if (s + 1 < s1) stage(s + 1, cur ^ 1);
      const char* kpc = (const char*)&KV[cur][0];
      const char* vpc = (const char*)&KV[cur][4096];

      f32x4 sv[2][4] = {};
      __builtin_amdgcn_s_setprio(1);
      #pragma unroll
      for (int kt = 0; kt < 2; kt++){
        bf16x8 kf[4];
        #pragma unroll
        for (int nf = 0; nf < 4; nf++){
          int row = nf*16 + lr;
          int cb  = (kt*64 + lg*16) ^ ((row & 7) << 4);
          kf[nf] = *(const bf16x8*)(kpc + row*128 + cb);
        }
        #pragma unroll
        for (int mf = 0; mf < 2; mf++)
          #pragma unroll
          for (int nf = 0; nf < 4; nf++)
            sv[mf][nf] = MFMA(qf[mf][kt], kf[nf], sv[mf][nf]);
      }
      __builtin_amdgcn_s_setprio(0);
      #pragma unroll
      for (int mf = 0; mf < 2; mf++)
        #pragma unroll
        for (int nfp = 0; nfp < 2; nfp++)
          #pragma unroll
          for (int r = 0; r < 4; r++){
            int nfA = nfp*2, nfB = nfp*2 + 1;
            float xa, xb_;
            if (btab){
              int qw = w*32 + mf*16 + lg*4 + r;
              xa = __builtin_fmaf(sv[mf][nfA][r], SC, btab[(qw << 8) + s*64 + nfA*16 + lr]);
              xb_= __builtin_fmaf(sv[mf][nfB][r], SC, btab[(qw << 8) + s*64 + nfB*16 + lr]);
            } else {
              xa = sv[mf][nfA][r] * SC;
              xb_= sv[mf][nfB][r] * SC;
            }
            unsigned pk = cvt_pk_bf16(fast_exp2(xa), fast_exp2(xb_));
            int row = mf*16 + lg*4 + r;
            int swz = (row & 7) << 4;
            *(unsigned short*)(pw + row*128 + (((nfA*16 + lr)*2) ^ swz)) = (unsigned short)pk;
            *(unsigned short*)(pw + row*128 + (((nfB*16 + lr)*2) ^ swz)) = (unsigned short)(pk >> 16);
          }
      #pragma unroll
      for (int kg = 0; kg < 2; kg++){
        bf16x8 pa[2], vf[4];
        #pragma unroll
        for (int mf = 0; mf < 2; mf++){
          int row = mf*16 + lr;
          int cb  = (kg*64 + lg*16) ^ ((row & 7) << 4);
          pa[mf] = *(const bf16x8*)(pw + row*128 + cb);
        }
        #pragma unroll
        for (int df = 0; df < 4; df++){
          int row = df*16 + lr;
          int cb  = (kg*64 + lg*16) ^ ((row & 7) << 4);
          vf[df] = *(const bf16x8*)(vpc + row*128 + cb);
        }
        __builtin_amdgcn_s_setprio(1);
        #pragma unroll
        for (int mf = 0; mf < 2; mf++){
          #pragma unroll
          for (int df = 0; df < 4; df++)
            ao[mf][df] = MFMA(pa[mf], vf[df], ao[mf][df]);
          lsum4[mf] = MFMA(pa[mf], ones8, lsum4[mf]);
        }
        __builtin_amdgcn_s_setprio(0);
      }
      asm volatile("s_waitcnt vmcnt(0)" ::: "memory");
      __builtin_amdgcn_s_barrier();
    }

    if (h == 0){
      #pragma unroll
      for (int mf = 0; mf < 2; mf++)
        #pragma unroll
        for (int r = 0; r < 4; r++){
          int qt = w*32 + mf*16 + lg*4 + r;
          size_t rowb = (((size_t)(b*4 + chunk)) << 12) + win*256 + qt;
          if (lr == 0) pl[rowb] = lsum4[mf][r];
          #pragma unroll
          for (int df = 0; df < 4; df++)
            pO[(rowb << 6) + df*16 + lr] = f2bf(ao[mf][df][r]);
        }
    } else {
      #pragma unroll
      for (int mf = 0; mf < 2; mf++)
        #pragma unroll
        for (int df = 0; df < 4; df++)
          #pragma unroll
          for (int r = 0; r < 4; r++){
            float o = ao[mf][df][r] / lsum4[mf][r];
            int qt = w*32 + mf*16 + lg*4 + r;
            int np = win*256 + qt;
            fsp[(((size_t)b*4096 + np) << 9) + h*64 + df*16 + lr] = f2bf(o);
          }
    }
  } else {
    // ================= h1..5: 2 window-units per block, 1 step, mf=1 =================
    int j = u - 96;
    int h = 1 + (j >> 5);
    int jj = j & 31;
    int ui = w >> 2, wi = w & 3;
    int u15 = jj*2 + ui;
    const size_t hb = ((size_t)(b*8 + h)) << 18;
    const float* bt = b64 + ((size_t)(h-1) << 12);
    char* base = (char*)&KV[0][0] + ui*16384;

    #pragma unroll
    for (int i = 0; i < 2; i++){
      int r = wi*16 + i*8 + (l >> 3);
      int sc = (((l & 7) ^ (r & 7)) << 3);
      gload16(kb  + hb + ((size_t)mapw(h, u15, r) << 6) + sc, base + (wi*16 + i*8)*128);
      gload16(vtb + hb + ((size_t)r << 12) + mapw(h, u15, sc), base + 8192 + (wi*16 + i*8)*128);
    }
    bf16x8 qf0, qf1;
    {
      int qt0 = wi*16 + lr;
      int nq = mapw(h, u15, qt0);
      const unsigned short* qp = qb + hb + ((size_t)nq << 6) + lg*8;
      qf0 = *(const bf16x8*)qp;
      qf1 = *(const bf16x8*)(qp + 32);
    }
    asm volatile("s_waitcnt vmcnt(0)" ::: "memory");
    __builtin_amdgcn_s_barrier();

    const char* kpc = base;
    const char* vpc = base + 8192;
    f32x4 ao4[4] = {};
    f32x4 ls = {};

    #pragma unroll
    for (int nfp = 0; nfp < 2; nfp++){
      f32x4 sv[2] = {};
      __builtin_amdgcn_s_setprio(1);
      #pragma unroll
      for (int kt = 0; kt < 2; kt++)
        #pragma unroll
        for (int nfi = 0; nfi < 2; nfi++){
          int row = (nfp*2 + nfi)*16 + lr;
          int cb  = (kt*64 + lg*16) ^ ((row & 7) << 4);
          bf16x8 kf = *(const bf16x8*)(kpc + row*128 + cb);
          sv[nfi] = MFMA(kt == 0 ? qf0 : qf1, kf, sv[nfi]);
        }
      __builtin_amdgcn_s_setprio(0);
      #pragma unroll
      for (int r = 0; r < 4; r++){
        int qw = wi*16 + lg*4 + r;
        float xa = __builtin_fmaf(sv[0][r], SC, bt[(qw << 6) + (nfp*2)*16 + lr]);
        float xb_= __builtin_fmaf(sv[1][r], SC, bt[(qw << 6) + (nfp*2+1)*16 + lr]);
        unsigned pk = cvt_pk_bf16(fast_exp2(xa), fast_exp2(xb_));
        int row = lg*4 + r;
        int swz = (row & 7) << 4;
        *(unsigned short*)(pw + row*128 + ((((nfp*2)*16 + lr)*2) ^ swz)) = (unsigned short)pk;
        *(unsigned short*)(pw + row*128 + ((((nfp*2+1)*16 + lr)*2) ^ swz)) = (unsigned short)(pk >> 16);
      }
    }
    #pragma unroll
    for (int kg = 0; kg < 2; kg++){
      bf16x8 pa;
      {
        int cb = (kg*64 + lg*16) ^ ((lr & 7) << 4);
        pa = *(const bf16x8*)(pw + lr*128 + cb);
      }
      __builtin_amdgcn_s_setprio(1);
      #pragma unroll
      for (int df = 0; df < 4; df++){
        int row = df*16 + lr;
        int cb  = (kg*64 + lg*16) ^ ((row & 7) << 4);
        bf16x8 vf = *(const bf16x8*)(vpc + row*128 + cb);
        ao4[df] = MFMA(pa, vf, ao4[df]);
      }
      ls = MFMA(pa, ones8, ls);
      __builtin_amdgcn_s_setprio(0);
    }
    #pragma unroll
    for (int df = 0; df < 4; df++)
      #pragma unroll
      for (int r = 0; r < 4; r++){
        float o = ao4[df][r] / ls[r];
        int qt = wi*16 + lg*4 + r;
        int np;
        if (h <= 2){
          int r4 = qt >> 4, w_ = (qt >> 2) & 3, c = qt & 3;
          np = (u15 >> 2)*256 + (u15 & 3)*64 + w_*16 + r4*4 + c;
        } else {
          np = u15*64 + qt;
        }
        fsp[(((size_t)b*4096 + np) << 9) + h*64 + df*16 + lr] = f2bf(o);
      }
  }
}

// ---------- combine head-0 KV chunks (4-way plain sums) ----------
__global__ __launch_bounds__(256)
void k_comb(const unsigned short* __restrict__ pO, const float* __restrict__ pl,
            unsigned short* __restrict__ fsp){
  int tid = blockIdx.x*256 + threadIdx.x;
  int d = tid & 63;
  int row = tid >> 6;
  int b = row >> 12;
  int n = row & 4095;
  float o = 0.f, L = 0.f;
  #pragma unroll
  for (int c = 0; c < 4; c++){
    size_t rr = (((size_t)(b*4 + c)) << 12) + n;
    L += pl[rr];
    o += bf2f(pO[(rr << 6) + d]);
  }
  o /= L;
  fsp[(((size_t)b*4096 + n) << 9) + d] = f2bf(o);
}

// ---------- launch ----------
extern "C" void kernel_launch(void* const* d_in, const int* in_sizes, int n_in,
                              void* d_out, int out_size, void* d_ws, size_t ws_size,
                              hipStream_t stream) {
  const float* x     = (const float*)d_in[0];
  const float* Wq    = (const float*)d_in[1];
  const float* Wkv   = (const float*)d_in[2];
  const float* Wp    = (const float*)d_in[3];
  const float* bproj = (const float*)d_in[4];
  const float* t1 = (const float*)d_in[7];
  const float* t2 = (const float*)d_in[8];
  const float* t3 = (const float*)d_in[9];
  const float* t4 = (const float*)d_in[10];
  const float* t5 = (const float*)d_in[11];
  const float* t6 = (const float*)d_in[12];
  const float* t7 = (const float*)d_in[13];

  char* W = (char*)d_ws;
  size_t off = 0;
  auto alloc = [&](size_t bytes)->char*{
    char* p = W + off; off += (bytes + 255) & ~(size_t)255; return p;
  };
  unsigned short* xb   = (unsigned short*)alloc((size_t)32768*512*2);   // dead after gemm0
  unsigned short* wqkv = (unsigned short*)alloc((size_t)1536*512*2);    // dead after gemm0
  unsigned short* wsp  = (unsigned short*)alloc((size_t)512*512*2);
  unsigned short* qbuf = (unsigned short*)alloc((size_t)8*8*4096*64*2);
  unsigned short* kbuf = (unsigned short*)alloc((size_t)8*8*4096*64*2);
  unsigned short* vtb  = (unsigned short*)alloc((size_t)8*8*4096*64*2);
  unsigned short* fsp  = (unsigned short*)alloc((size_t)32768*512*2);
  float* b64  = (float*)alloc((size_t)5*64*64*4);
  float* b256 = (float*)alloc((size_t)2*256*256*4);
  if (off > ws_size) return;

  unsigned short* pO = xb;                 // 32 chunk-units * 4096 rows * 64 d * 2B = 16 MiB
  float* pl = (float*)wqkv;                // 32*4096*4B = 512 KiB

  k_prep<<<8192, 256, 0, stream>>>(x, xb, Wq, Wkv, Wp, t1,t2,t3,t4,t5,t6,t7,
                                   wqkv, wsp, b64, b256);
  k_gemm<0><<<3072, 256, 0, stream>>>(xb, wqkv, 32768,
                                      qbuf, kbuf, vtb, nullptr, nullptr);
  k_attn<<<2048, 512, 0, stream>>>(qbuf, kbuf, vtb, b64, b256, fsp, pO, pl);
  k_comb<<<8192, 256, 0, stream>>>(pO, pl, fsp);
  k_gemm<1><<<1024, 256, 0, stream>>>(fsp, wsp, 32768,
                                      nullptr, nullptr, nullptr, (float*)d_out, bproj);
}

// Round 19
// 241.003 us; speedup vs baseline: 1.0621x; 1.0372x over previous
//
#include <hip/hip_runtime.h>
#include <stdint.h>

typedef __attribute__((ext_vector_type(8))) short bf16x8;
typedef __attribute__((ext_vector_type(4))) float f32x4;

#define LOG2E 1.4426950408889634f

__device__ __forceinline__ unsigned short f2bf(float f){
  union { float f; unsigned u; } v; v.f = f;
  return (unsigned short)((v.u + 0x7fffu + ((v.u >> 16) & 1u)) >> 16);
}
__device__ __forceinline__ float bf2f(unsigned short h){
  union { unsigned u; float f; } v; v.u = ((unsigned)h) << 16; return v.f;
}
__device__ __forceinline__ float fast_exp2(float x){
  float r; asm("v_exp_f32 %0, %1" : "=v"(r) : "v"(x)); return r;
}
__device__ __forceinline__ unsigned cvt_pk_bf16(float lo, float hi){
  unsigned r; asm("v_cvt_pk_bf16_f32 %0, %1, %2" : "=v"(r) : "v"(lo), "v"(hi)); return r;
}
__device__ __forceinline__ void gload16(const void* g, void* lds){
  __builtin_amdgcn_global_load_lds((const __attribute__((address_space(1))) unsigned int*)g,
                                   (__attribute__((address_space(3))) unsigned int*)lds,
                                   16, 0, 0);
}
#define MFMA(a,b,c) __builtin_amdgcn_mfma_f32_16x16x32_bf16((a),(b),(c),0,0,0)

// B=8, H=W=64, N=4096, C=512, nh=8, hd=64

// Merged prep: x->bf16 + weights + bias tables (pre-scaled by log2(e)).
__global__ __launch_bounds__(256)
void k_prep(const float* __restrict__ x, unsigned short* __restrict__ xb,
            const float* __restrict__ Wq, const float* __restrict__ Wkv,
            const float* __restrict__ Wp,
            const float* t1,const float* t2,const float* t3,const float* t4,
            const float* t5,const float* t6,const float* t7,
            unsigned short* __restrict__ wqkv, unsigned short* __restrict__ wsp,
            float* __restrict__ b64, float* __restrict__ b256){
  int gid = blockIdx.x*256 + threadIdx.x;
  int stride = gridDim.x*256;
  int i8 = gid*8;
  if (i8 < 32768*512){
    float4 a = *(const float4*)(x+i8);
    float4 bb = *(const float4*)(x+i8+4);
    *(ushort4*)(xb+i8)   = make_ushort4(f2bf(a.x), f2bf(a.y), f2bf(a.z), f2bf(a.w));
    *(ushort4*)(xb+i8+4) = make_ushort4(f2bf(bb.x), f2bf(bb.y), f2bf(bb.z), f2bf(bb.w));
  }
  for (int e = gid; e < 1536*512; e += stride){
    int r = e >> 9;
    wqkv[e] = f2bf(r < 512 ? Wq[e] : Wkv[e - 512*512]);
  }
  for (int e = gid; e < 512*512; e += stride)
    wsp[e] = f2bf(Wp[e]);
  for (int e = gid; e < 5*4096; e += stride){
    int hh = e >> 12;
    int q = (e >> 6) & 63, kk = e & 63;
    float v;
    if (hh < 2){
      const float* tb = hh ? t2 : t1;
      int r1=q>>4, i1=(q>>2)&3, c1=q&3;
      int r2=kk>>4, i2=(kk>>2)&3, c2=kk&3;
      v = (i1==i2) ? tb[(r1-r2+3)*7 + (c1-c2+3)] : -1e30f;
    } else {
      const float* tb = (hh==2)?t3:((hh==3)?t4:t5);
      int r1=q>>3, c1=q&7, r2=kk>>3, c2=kk&7;
      v = tb[(r1-r2+7)*15 + (c1-c2+7)];
    }
    b64[e] = v * LOG2E;
  }
  for (int e = gid; e < 2*65536; e += stride){
    int hh = e >> 16; int q = (e >> 8) & 255, kk = e & 255;
    const float* tb = hh ? t7 : t6;
    int r1=q>>4, c1=q&15, r2=kk>>4, c2=kk&15;
    b256[e] = tb[(r1-r2+15)*31 + (c1-c2+15)] * LOG2E;
  }
}

// ---------- GEMM (validated machinery), A-panel-major XCD-chunked block mapping ----------
// Old mapping streamed A 12x (gemm0) / 4x (gemm1) from HBM. New: the nt blocks sharing
// one 128KB A-panel run concurrently on one XCD -> A fetched once into its L2.
template<int EPI>
__global__ __launch_bounds__(256, 2)
void k_gemm(const unsigned short* __restrict__ A, const unsigned short* __restrict__ Bw,
            int M,
            unsigned short* __restrict__ oq, unsigned short* __restrict__ ok,
            unsigned short* __restrict__ ovt,
            float* __restrict__ of, const float* __restrict__ bias)
{
  __shared__ unsigned short As[128*64];
  __shared__ unsigned short Bs[128*64];
  const int t = threadIdx.x, l = t & 63, w = t >> 6;
  const int mt = M >> 7;
  const int nt = (EPI == 0) ? 12 : 4;
  const int xcd = blockIdx.x & 7;
  const int idx = blockIdx.x >> 3;
  const int bm = xcd*(mt >> 3) + idx / nt;
  const int bn = idx % nt;
  const int m0 = bm << 7, n0 = bn << 7;
  const int wr = w >> 1, wc = w & 1;
  const int lr = l & 15, lg = l >> 4;
  f32x4 acc[4][4] = {};

  for (int k0 = 0; k0 < 512; k0 += 64){
    #pragma unroll
    for (int i = 0; i < 4; i++){
      int rowb = i*32 + w*8;
      int row  = rowb + (l >> 3);
      int sc   = (((l & 7) ^ (row & 7)) << 3);
      gload16(A  + (size_t)(m0 + row)*512 + k0 + sc, &As[rowb*64]);
      gload16(Bw + (size_t)(n0 + row)*512 + k0 + sc, &Bs[rowb*64]);
    }
    __syncthreads();
    #pragma unroll
    for (int kt = 0; kt < 2; kt++){
      bf16x8 af[4], bfr[4];
      #pragma unroll
      for (int mi = 0; mi < 4; mi++){
        int row = wr*64 + mi*16 + lr;
        int cb  = (kt*64 + lg*16) ^ ((row & 7) << 4);
        af[mi] = *(const bf16x8*)((const char*)As + row*128 + cb);
      }
      #pragma unroll
      for (int ni = 0; ni < 4; ni++){
        int row = wc*64 + ni*16 + lr;
        int cb  = (kt*64 + lg*16) ^ ((row & 7) << 4);
        bfr[ni] = *(const bf16x8*)((const char*)Bs + row*128 + cb);
      }
      #pragma unroll
      for (int mi = 0; mi < 4; mi++)
        #pragma unroll
        for (int ni = 0; ni < 4; ni++)
          acc[mi][ni] = MFMA(af[mi], bfr[ni], acc[mi][ni]);
    }
    __syncthreads();
  }

  #pragma unroll
  for (int mi = 0; mi < 4; mi++){
    #pragma unroll
    for (int ni = 0; ni < 4; ni++){
      int m = m0 + wr*64 + mi*16 + lg*4;
      int o = n0 + wc*64 + ni*16 + lr;
      if (EPI == 0){
        int which = o >> 9, oo = o & 511, h = oo >> 6, d = oo & 63;
        int b_ = m >> 12, n_ = m & 4095;
        if (which == 2){
          *(ushort4*)(ovt + ((((size_t)b_*8 + h)*64 + d) << 12) + n_) =
            make_ushort4(f2bf(acc[mi][ni][0]), f2bf(acc[mi][ni][1]),
                         f2bf(acc[mi][ni][2]), f2bf(acc[mi][ni][3]));
        } else {
          unsigned short* dst = (which == 0) ? oq : ok;
          size_t base = (((size_t)(b_*8 + h)) << 18) + ((size_t)n_ << 6) + d;
          #pragma unroll
          for (int r = 0; r < 4; r++)
            dst[base + (size_t)r*64] = f2bf(acc[mi][ni][r]);
        }
      } else {
        float bv = bias[o];
        #pragma unroll
        for (int r = 0; r < 4; r++)
          of[(size_t)(m + r)*512 + o] = acc[mi][ni][r] + bv;
      }
    }
  }
}

// ---------- unified attention (R18, validated: 123 us, 0 bank conflicts) ----------
__device__ __forceinline__ int map16(int win, int t){
  return (((win >> 2)*16 + (t >> 4)) << 6) + ((win & 3) << 4) + (t & 15);
}
__device__ __forceinline__ int mapw(int h, int u, int t){
  if (h <= 2) return (((u >> 2)*4 + (t >> 4)) << 6) + ((u & 3) << 4) + (t & 15);
  return (((u >> 3)*8 + (t >> 3)) << 6) + ((u & 7) << 3) + (t & 7);
}

__global__ __launch_bounds__(512)
void k_attn(const unsigned short* __restrict__ qb, const unsigned short* __restrict__ kb,
            const unsigned short* __restrict__ vtb,
            const float* __restrict__ b64, const float* __restrict__ b256,
            unsigned short* __restrict__ fsp,
            unsigned short* __restrict__ pO, float* __restrict__ pl)
{
  __shared__ unsigned short KV[2][8192];
  __shared__ unsigned short Pp[8][2048];
  const int t = threadIdx.x, l = t & 63, w = t >> 6;
  const int lr = l & 15, lg = l >> 4;
  const int v = (blockIdx.x & 7)*256 + (blockIdx.x >> 3);   // XCD-pinned, 2048 blocks
  const int b = v / 256, u = v % 256;
  const float SC = 0.125f * LOG2E;
  char* pw = (char*)Pp[w];
  bf16x8 ones8;
  #pragma unroll
  for (int e = 0; e < 8; e++) ones8[e] = (short)0x3F80;

  if (u < 96){
    int h, win, s0, s1, chunk = 0;
    const float* btab = nullptr;
    if (u < 64){ h = 0; win = u >> 2; chunk = u & 3; s0 = chunk*16; s1 = s0 + 16; }
    else { int uu = u - 64; h = 6 + (uu >> 4); win = uu & 15; s0 = 0; s1 = 4;
           btab = b256 + ((size_t)(h - 6) << 16); }
    const size_t hb = ((size_t)(b*8 + h)) << 18;

    const int srow = w*8 + (l >> 3);
    const int ssc  = (((l & 7) ^ (srow & 7)) << 3);

    bf16x8 qf[2][2];
    #pragma unroll
    for (int mf = 0; mf < 2; mf++){
      int qt = w*32 + mf*16 + lr;
      int n = (h == 0) ? (win*256 + qt) : map16(win, qt);
      const unsigned short* qp = qb + hb + ((size_t)n << 6) + lg*8;
      qf[mf][0] = *(const bf16x8*)qp;
      qf[mf][1] = *(const bf16x8*)(qp + 32);
    }
    f32x4 ao[2][4] = {};
    f32x4 lsum4[2] = {};

    auto stage = [&](int s, int buf){
      int tk = s*64 + srow;
      int nk = (h == 0) ? tk : map16(win, tk);
      gload16(kb + hb + ((size_t)nk << 6) + ssc, &KV[buf][w*512]);
      int tv = s*64 + ssc;
      int nv = (h == 0) ? tv : map16(win, tv);
      gload16(vtb + hb + ((size_t)srow << 12) + nv, &KV[buf][4096 + w*512]);
    };

    stage(s0, 0);
    asm volatile("s_waitcnt vmcnt(0)" ::: "memory");
    __builtin_amdgcn_s_barrier();

    for (int s = s0; s < s1; s++){
      const int cur = (s - s0) & 1;
      if (s + 1 < s1) stage(s + 1, cur ^ 1);
      const char* kpc = (const char*)&KV[cur][0];
      const char* vpc = (const char*)&KV[cur][4096];

      f32x4 sv[2][4] = {};
      __builtin_amdgcn_s_setprio(1);
      #pragma unroll
      for (int kt = 0; kt < 2; kt++){
        bf16x8 kf[4];
        #pragma unroll
        for (int nf = 0; nf < 4; nf++){
          int row = nf*16 + lr;
          int cb  = (kt*64 + lg*16) ^ ((row & 7) << 4);
          kf[nf] = *(const bf16x8*)(kpc + row*128 + cb);
        }
        #pragma unroll
        for (int mf = 0; mf < 2; mf++)
          #pragma unroll
          for (int nf = 0; nf < 4; nf++)
            sv[mf][nf] = MFMA(qf[mf][kt], kf[nf], sv[mf][nf]);
      }
      __builtin_amdgcn_s_setprio(0);
      #pragma unroll
      for (int mf = 0; mf < 2; mf++)
        #pragma unroll
        for (int nfp = 0; nfp < 2; nfp++)
          #pragma unroll
          for (int r = 0; r < 4; r++){
            int nfA = nfp*2, nfB = nfp*2 + 1;
            float xa, xb_;
            if (btab){
              int qw = w*32 + mf*16 + lg*4 + r;
              xa = __builtin_fmaf(sv[mf][nfA][r], SC, btab[(qw << 8) + s*64 + nfA*16 + lr]);
              xb_= __builtin_fmaf(sv[mf][nfB][r], SC, btab[(qw << 8) + s*64 + nfB*16 + lr]);
            } else {
              xa = sv[mf][nfA][r] * SC;
              xb_= sv[mf][nfB][r] * SC;
            }
            unsigned pk = cvt_pk_bf16(fast_exp2(xa), fast_exp2(xb_));
            int row = mf*16 + lg*4 + r;
            int swz = (row & 7) << 4;
            *(unsigned short*)(pw + row*128 + (((nfA*16 + lr)*2) ^ swz)) = (unsigned short)pk;
            *(unsigned short*)(pw + row*128 + (((nfB*16 + lr)*2) ^ swz)) = (unsigned short)(pk >> 16);
          }
      #pragma unroll
      for (int kg = 0; kg < 2; kg++){
        bf16x8 pa[2], vf[4];
        #pragma unroll
        for (int mf = 0; mf < 2; mf++){
          int row = mf*16 + lr;
          int cb  = (kg*64 + lg*16) ^ ((row & 7) << 4);
          pa[mf] = *(const bf16x8*)(pw + row*128 + cb);
        }
        #pragma unroll
        for (int df = 0; df < 4; df++){
          int row = df*16 + lr;
          int cb  = (kg*64 + lg*16) ^ ((row & 7) << 4);
          vf[df] = *(const bf16x8*)(vpc + row*128 + cb);
        }
        __builtin_amdgcn_s_setprio(1);
        #pragma unroll
        for (int mf = 0; mf < 2; mf++){
          #pragma unroll
          for (int df = 0; df < 4; df++)
            ao[mf][df] = MFMA(pa[mf], vf[df], ao[mf][df]);
          lsum4[mf] = MFMA(pa[mf], ones8, lsum4[mf]);
        }
        __builtin_amdgcn_s_setprio(0);
      }
      asm volatile("s_waitcnt vmcnt(0)" ::: "memory");
      __builtin_amdgcn_s_barrier();
    }

    if (h == 0){
      #pragma unroll
      for (int mf = 0; mf < 2; mf++)
        #pragma unroll
        for (int r = 0; r < 4; r++){
          int qt = w*32 + mf*16 + lg*4 + r;
          size_t rowb = (((size_t)(b*4 + chunk)) << 12) + win*256 + qt;
          if (lr == 0) pl[rowb] = lsum4[mf][r];
          #pragma unroll
          for (int df = 0; df < 4; df++)
            pO[(rowb << 6) + df*16 + lr] = f2bf(ao[mf][df][r]);
        }
    } else {
      #pragma unroll
      for (int mf = 0; mf < 2; mf++)
        #pragma unroll
        for (int df = 0; df < 4; df++)
          #pragma unroll
          for (int r = 0; r < 4; r++){
            float o = ao[mf][df][r] / lsum4[mf][r];
            int qt = w*32 + mf*16 + lg*4 + r;
            int np = win*256 + qt;
            fsp[(((size_t)b*4096 + np) << 9) + h*64 + df*16 + lr] = f2bf(o);
          }
    }
  } else {
    int j = u - 96;
    int h = 1 + (j >> 5);
    int jj = j & 31;
    int ui = w >> 2, wi = w & 3;
    int u15 = jj*2 + ui;
    const size_t hb = ((size_t)(b*8 + h)) << 18;
    const float* bt = b64 + ((size_t)(h-1) << 12);
    char* base = (char*)&KV[0][0] + ui*16384;

    #pragma unroll
    for (int i = 0; i < 2; i++){
      int r = wi*16 + i*8 + (l >> 3);
      int sc = (((l & 7) ^ (r & 7)) << 3);
      gload16(kb  + hb + ((size_t)mapw(h, u15, r) << 6) + sc, base + (wi*16 + i*8)*128);
      gload16(vtb + hb + ((size_t)r << 12) + mapw(h, u15, sc), base + 8192 + (wi*16 + i*8)*128);
    }
    bf16x8 qf0, qf1;
    {
      int qt0 = wi*16 + lr;
      int nq = mapw(h, u15, qt0);
      const unsigned short* qp = qb + hb + ((size_t)nq << 6) + lg*8;
      qf0 = *(const bf16x8*)qp;
      qf1 = *(const bf16x8*)(qp + 32);
    }
    asm volatile("s_waitcnt vmcnt(0)" ::: "memory");
    __builtin_amdgcn_s_barrier();

    const char* kpc = base;
    const char* vpc = base + 8192;
    f32x4 ao4[4] = {};
    f32x4 ls = {};

    #pragma unroll
    for (int nfp = 0; nfp < 2; nfp++){
      f32x4 sv[2] = {};
      __builtin_amdgcn_s_setprio(1);
      #pragma unroll
      for (int kt = 0; kt < 2; kt++)
        #pragma unroll
        for (int nfi = 0; nfi < 2; nfi++){
          int row = (nfp*2 + nfi)*16 + lr;
          int cb  = (kt*64 + lg*16) ^ ((row & 7) << 4);
          bf16x8 kf = *(const bf16x8*)(kpc + row*128 + cb);
          sv[nfi] = MFMA(kt == 0 ? qf0 : qf1, kf, sv[nfi]);
        }
      __builtin_amdgcn_s_setprio(0);
      #pragma unroll
      for (int r = 0; r < 4; r++){
        int qw = wi*16 + lg*4 + r;
        float xa = __builtin_fmaf(sv[0][r], SC, bt[(qw << 6) + (nfp*2)*16 + lr]);
        float xb_= __builtin_fmaf(sv[1][r], SC, bt[(qw << 6) + (nfp*2+1)*16 + lr]);
        unsigned pk = cvt_pk_bf16(fast_exp2(xa), fast_exp2(xb_));
        int row = lg*4 + r;
        int swz = (row & 7) << 4;
        *(unsigned short*)(pw + row*128 + ((((nfp*2)*16 + lr)*2) ^ swz)) = (unsigned short)pk;
        *(unsigned short*)(pw + row*128 + ((((nfp*2+1)*16 + lr)*2) ^ swz)) = (unsigned short)(pk >> 16);
      }
    }
    #pragma unroll
    for (int kg = 0; kg < 2; kg++){
      bf16x8 pa;
      {
        int cb = (kg*64 + lg*16) ^ ((lr & 7) << 4);
        pa = *(const bf16x8*)(pw + lr*128 + cb);
      }
      __builtin_amdgcn_s_setprio(1);
      #pragma unroll
      for (int df = 0; df < 4; df++){
        int row = df*16 + lr;
        int cb  = (kg*64 + lg*16) ^ ((row & 7) << 4);
        bf16x8 vf = *(const bf16x8*)(vpc + row*128 + cb);
        ao4[df] = MFMA(pa, vf, ao4[df]);
      }
      ls = MFMA(pa, ones8, ls);
      __builtin_amdgcn_s_setprio(0);
    }
    #pragma unroll
    for (int df = 0; df < 4; df++)
      #pragma unroll
      for (int r = 0; r < 4; r++){
        float o = ao4[df][r] / ls[r];
        int qt = wi*16 + lg*4 + r;
        int np;
        if (h <= 2){
          int r4 = qt >> 4, w_ = (qt >> 2) & 3, c = qt & 3;
          np = (u15 >> 2)*256 + (u15 & 3)*64 + w_*16 + r4*4 + c;
        } else {
          np = u15*64 + qt;
        }
        fsp[(((size_t)b*4096 + np) << 9) + h*64 + df*16 + lr] = f2bf(o);
      }
  }
}

// ---------- combine head-0 KV chunks (4-way plain sums) ----------
__global__ __launch_bounds__(256)
void k_comb(const unsigned short* __restrict__ pO, const float* __restrict__ pl,
            unsigned short* __restrict__ fsp){
  int tid = blockIdx.x*256 + threadIdx.x;
  int d = tid & 63;
  int row = tid >> 6;
  int b = row >> 12;
  int n = row & 4095;
  float o = 0.f, L = 0.f;
  #pragma unroll
  for (int c = 0; c < 4; c++){
    size_t rr = (((size_t)(b*4 + c)) << 12) + n;
    L += pl[rr];
    o += bf2f(pO[(rr << 6) + d]);
  }
  o /= L;
  fsp[(((size_t)b*4096 + n) << 9) + d] = f2bf(o);
}

// ---------- launch ----------
extern "C" void kernel_launch(void* const* d_in, const int* in_sizes, int n_in,
                              void* d_out, int out_size, void* d_ws, size_t ws_size,
                              hipStream_t stream) {
  const float* x     = (const float*)d_in[0];
  const float* Wq    = (const float*)d_in[1];
  const float* Wkv   = (const float*)d_in[2];
  const float* Wp    = (const float*)d_in[3];
  const float* bproj = (const float*)d_in[4];
  const float* t1 = (const float*)d_in[7];
  const float* t2 = (const float*)d_in[8];
  const float* t3 = (const float*)d_in[9];
  const float* t4 = (const float*)d_in[10];
  const float* t5 = (const float*)d_in[11];
  const float* t6 = (const float*)d_in[12];
  const float* t7 = (const float*)d_in[13];

  char* W = (char*)d_ws;
  size_t off = 0;
  auto alloc = [&](size_t bytes)->char*{
    char* p = W + off; off += (bytes + 255) & ~(size_t)255; return p;
  };
  unsigned short* xb   = (unsigned short*)alloc((size_t)32768*512*2);   // dead after gemm0
  unsigned short* wqkv = (unsigned short*)alloc((size_t)1536*512*2);    // dead after gemm0
  unsigned short* wsp  = (unsigned short*)alloc((size_t)512*512*2);
  unsigned short* qbuf = (unsigned short*)alloc((size_t)8*8*4096*64*2);
  unsigned short* kbuf = (unsigned short*)alloc((size_t)8*8*4096*64*2);
  unsigned short* vtb  = (unsigned short*)alloc((size_t)8*8*4096*64*2);
  unsigned short* fsp  = (unsigned short*)alloc((size_t)32768*512*2);
  float* b64  = (float*)alloc((size_t)5*64*64*4);
  float* b256 = (float*)alloc((size_t)2*256*256*4);
  if (off > ws_size) return;

  unsigned short* pO = xb;                 // 32 chunk-units * 4096 rows * 64 d * 2B = 16 MiB
  float* pl = (float*)wqkv;                // 32*4096*4B = 512 KiB

  k_prep<<<8192, 256, 0, stream>>>(x, xb, Wq, Wkv, Wp, t1,t2,t3,t4,t5,t6,t7,
                                   wqkv, wsp, b64, b256);
  k_gemm<0><<<3072, 256, 0, stream>>>(xb, wqkv, 32768,
                                      qbuf, kbuf, vtb, nullptr, nullptr);
  k_attn<<<2048, 512, 0, stream>>>(qbuf, kbuf, vtb, b64, b256, fsp, pO, pl);
  k_comb<<<8192, 256, 0, stream>>>(pO, pl, fsp);
  k_gemm<1><<<1024, 256, 0, stream>>>(fsp, wsp, 32768,
                                      nullptr, nullptr, nullptr, (float*)d_out, bproj);
}

// Round 20
// 236.668 us; speedup vs baseline: 1.0815x; 1.0183x over previous
//
#include <hip/hip_runtime.h>
#include <stdint.h>

typedef __attribute__((ext_vector_type(8))) short bf16x8;
typedef __attribute__((ext_vector_type(4))) float f32x4;

#define LOG2E 1.4426950408889634f

__device__ __forceinline__ unsigned short f2bf(float f){
  union { float f; unsigned u; } v; v.f = f;
  return (unsigned short)((v.u + 0x7fffu + ((v.u >> 16) & 1u)) >> 16);
}
__device__ __forceinline__ float bf2f(unsigned short h){
  union { unsigned u; float f; } v; v.u = ((unsigned)h) << 16; return v.f;
}
__device__ __forceinline__ float fast_exp2(float x){
  float r; asm("v_exp_f32 %0, %1" : "=v"(r) : "v"(x)); return r;
}
__device__ __forceinline__ unsigned cvt_pk_bf16(float lo, float hi){
  unsigned r; asm("v_cvt_pk_bf16_f32 %0, %1, %2" : "=v"(r) : "v"(lo), "v"(hi)); return r;
}
__device__ __forceinline__ void gload16(const void* g, void* lds){
  __builtin_amdgcn_global_load_lds((const __attribute__((address_space(1))) unsigned int*)g,
                                   (__attribute__((address_space(3))) unsigned int*)lds,
                                   16, 0, 0);
}
#define MFMA(a,b,c) __builtin_amdgcn_mfma_f32_16x16x32_bf16((a),(b),(c),0,0,0)

// B=8, H=W=64, N=4096, C=512, nh=8, hd=64

// Merged prep: x->bf16 + weights + bias tables (pre-scaled by log2(e)).
__global__ __launch_bounds__(256)
void k_prep(const float* __restrict__ x, unsigned short* __restrict__ xb,
            const float* __restrict__ Wq, const float* __restrict__ Wkv,
            const float* __restrict__ Wp,
            const float* t1,const float* t2,const float* t3,const float* t4,
            const float* t5,const float* t6,const float* t7,
            unsigned short* __restrict__ wqkv, unsigned short* __restrict__ wsp,
            float* __restrict__ b64, float* __restrict__ b256){
  int gid = blockIdx.x*256 + threadIdx.x;
  int stride = gridDim.x*256;
  int i8 = gid*8;
  if (i8 < 32768*512){
    float4 a = *(const float4*)(x+i8);
    float4 bb = *(const float4*)(x+i8+4);
    *(ushort4*)(xb+i8)   = make_ushort4(f2bf(a.x), f2bf(a.y), f2bf(a.z), f2bf(a.w));
    *(ushort4*)(xb+i8+4) = make_ushort4(f2bf(bb.x), f2bf(bb.y), f2bf(bb.z), f2bf(bb.w));
  }
  for (int e = gid; e < 1536*512; e += stride){
    int r = e >> 9;
    wqkv[e] = f2bf(r < 512 ? Wq[e] : Wkv[e - 512*512]);
  }
  for (int e = gid; e < 512*512; e += stride)
    wsp[e] = f2bf(Wp[e]);
  for (int e = gid; e < 5*4096; e += stride){
    int hh = e >> 12;
    int q = (e >> 6) & 63, kk = e & 63;
    float v;
    if (hh < 2){
      const float* tb = hh ? t2 : t1;
      int r1=q>>4, i1=(q>>2)&3, c1=q&3;
      int r2=kk>>4, i2=(kk>>2)&3, c2=kk&3;
      v = (i1==i2) ? tb[(r1-r2+3)*7 + (c1-c2+3)] : -1e30f;
    } else {
      const float* tb = (hh==2)?t3:((hh==3)?t4:t5);
      int r1=q>>3, c1=q&7, r2=kk>>3, c2=kk&7;
      v = tb[(r1-r2+7)*15 + (c1-c2+7)];
    }
    b64[e] = v * LOG2E;
  }
  for (int e = gid; e < 2*65536; e += stride){
    int hh = e >> 16; int q = (e >> 8) & 255, kk = e & 255;
    const float* tb = hh ? t7 : t6;
    int r1=q>>4, c1=q&15, r2=kk>>4, c2=kk&15;
    b256[e] = tb[(r1-r2+15)*31 + (c1-c2+15)] * LOG2E;
  }
}

// ---------- GEMM (validated machinery), A-panel-major XCD-chunked block mapping ----------
template<int EPI>
__global__ __launch_bounds__(256, 2)
void k_gemm(const unsigned short* __restrict__ A, const unsigned short* __restrict__ Bw,
            int M,
            unsigned short* __restrict__ oq, unsigned short* __restrict__ ok,
            unsigned short* __restrict__ ovt,
            float* __restrict__ of, const float* __restrict__ bias)
{
  __shared__ unsigned short As[128*64];
  __shared__ unsigned short Bs[128*64];
  const int t = threadIdx.x, l = t & 63, w = t >> 6;
  const int mt = M >> 7;
  const int nt = (EPI == 0) ? 12 : 4;
  const int xcd = blockIdx.x & 7;
  const int idx = blockIdx.x >> 3;
  const int bm = xcd*(mt >> 3) + idx / nt;
  const int bn = idx % nt;
  const int m0 = bm << 7, n0 = bn << 7;
  const int wr = w >> 1, wc = w & 1;
  const int lr = l & 15, lg = l >> 4;
  f32x4 acc[4][4] = {};

  for (int k0 = 0; k0 < 512; k0 += 64){
    #pragma unroll
    for (int i = 0; i < 4; i++){
      int rowb = i*32 + w*8;
      int row  = rowb + (l >> 3);
      int sc   = (((l & 7) ^ (row & 7)) << 3);
      gload16(A  + (size_t)(m0 + row)*512 + k0 + sc, &As[rowb*64]);
      gload16(Bw + (size_t)(n0 + row)*512 + k0 + sc, &Bs[rowb*64]);
    }
    __syncthreads();
    #pragma unroll
    for (int kt = 0; kt < 2; kt++){
      bf16x8 af[4], bfr[4];
      #pragma unroll
      for (int mi = 0; mi < 4; mi++){
        int row = wr*64 + mi*16 + lr;
        int cb  = (kt*64 + lg*16) ^ ((row & 7) << 4);
        af[mi] = *(const bf16x8*)((const char*)As + row*128 + cb);
      }
      #pragma unroll
      for (int ni = 0; ni < 4; ni++){
        int row = wc*64 + ni*16 + lr;
        int cb  = (kt*64 + lg*16) ^ ((row & 7) << 4);
        bfr[ni] = *(const bf16x8*)((const char*)Bs + row*128 + cb);
      }
      #pragma unroll
      for (int mi = 0; mi < 4; mi++)
        #pragma unroll
        for (int ni = 0; ni < 4; ni++)
          acc[mi][ni] = MFMA(af[mi], bfr[ni], acc[mi][ni]);
    }
    __syncthreads();
  }

  #pragma unroll
  for (int mi = 0; mi < 4; mi++){
    #pragma unroll
    for (int ni = 0; ni < 4; ni++){
      int m = m0 + wr*64 + mi*16 + lg*4;
      int o = n0 + wc*64 + ni*16 + lr;
      if (EPI == 0){
        int which = o >> 9, oo = o & 511, h = oo >> 6, d = oo & 63;
        int b_ = m >> 12, n_ = m & 4095;
        if (which == 2){
          *(ushort4*)(ovt + ((((size_t)b_*8 + h)*64 + d) << 12) + n_) =
            make_ushort4(f2bf(acc[mi][ni][0]), f2bf(acc[mi][ni][1]),
                         f2bf(acc[mi][ni][2]), f2bf(acc[mi][ni][3]));
        } else {
          unsigned short* dst = (which == 0) ? oq : ok;
          size_t base = (((size_t)(b_*8 + h)) << 18) + ((size_t)n_ << 6) + d;
          #pragma unroll
          for (int r = 0; r < 4; r++)
            dst[base + (size_t)r*64] = f2bf(acc[mi][ni][r]);
        }
      } else {
        float bv = bias[o];
        #pragma unroll
        for (int r = 0; r < 4; r++)
          of[(size_t)(m + r)*512 + o] = acc[mi][ni][r] + bv;
      }
    }
  }
}

// ---------- unified attention: h0 now 2-way KV-chunked (32 steps) ----------
__device__ __forceinline__ int map16(int win, int t){
  return (((win >> 2)*16 + (t >> 4)) << 6) + ((win & 3) << 4) + (t & 15);
}
__device__ __forceinline__ int mapw(int h, int u, int t){
  if (h <= 2) return (((u >> 2)*4 + (t >> 4)) << 6) + ((u & 3) << 4) + (t & 15);
  return (((u >> 3)*8 + (t >> 3)) << 6) + ((u & 7) << 3) + (t & 7);
}

__global__ __launch_bounds__(512)
void k_attn(const unsigned short* __restrict__ qb, const unsigned short* __restrict__ kb,
            const unsigned short* __restrict__ vtb,
            const float* __restrict__ b64, const float* __restrict__ b256,
            unsigned short* __restrict__ fsp,
            unsigned short* __restrict__ pO, float* __restrict__ pl)
{
  __shared__ unsigned short KV[2][8192];
  __shared__ unsigned short Pp[8][2048];
  const int t = threadIdx.x, l = t & 63, w = t >> 6;
  const int lr = l & 15, lg = l >> 4;
  const int v = (blockIdx.x & 7)*224 + (blockIdx.x >> 3);   // XCD-pinned, 1792 blocks
  const int b = v / 224, u = v % 224;
  const float SC = 0.125f * LOG2E;
  char* pw = (char*)Pp[w];
  bf16x8 ones8;
  #pragma unroll
  for (int e = 0; e < 8; e++) ones8[e] = (short)0x3F80;

  if (u < 64){
    int h, win, s0, s1, chunk = 0;
    const float* btab = nullptr;
    if (u < 32){ h = 0; win = u >> 1; chunk = u & 1; s0 = chunk*32; s1 = s0 + 32; }
    else { int uu = u - 32; h = 6 + (uu >> 4); win = uu & 15; s0 = 0; s1 = 4;
           btab = b256 + ((size_t)(h - 6) << 16); }
    const size_t hb = ((size_t)(b*8 + h)) << 18;

    const int srow = w*8 + (l >> 3);
    const int ssc  = (((l & 7) ^ (srow & 7)) << 3);

    bf16x8 qf[2][2];
    #pragma unroll
    for (int mf = 0; mf < 2; mf++){
      int qt = w*32 + mf*16 + lr;
      int n = (h == 0) ? (win*256 + qt) : map16(win, qt);
      const unsigned short* qp = qb + hb + ((size_t)n << 6) + lg*8;
      qf[mf][0] = *(const bf16x8*)qp;
      qf[mf][1] = *(const bf16x8*)(qp + 32);
    }
    f32x4 ao[2][4] = {};
    f32x4 lsum4[2] = {};

    auto stage = [&](int s, int buf){
      int tk = s*64 + srow;
      int nk = (h == 0) ? tk : map16(win, tk);
      gload16(kb + hb + ((size_t)nk << 6) + ssc, &KV[buf][w*512]);
      int tv = s*64 + ssc;
      int nv = (h == 0) ? tv : map16(win, tv);
      gload16(vtb + hb + ((size_t)srow << 12) + nv, &KV[buf][4096 + w*512]);
    };

    stage(s0, 0);
    asm volatile("s_waitcnt vmcnt(0)" ::: "memory");
    __builtin_amdgcn_s_barrier();

    for (int s = s0; s < s1; s++){
      const int cur = (s - s0) & 1;
      if (s + 1 < s1) stage(s + 1, cur ^ 1);
      const char* kpc = (const char*)&KV[cur][0];
      const char* vpc = (const char*)&KV[cur][4096];

      f32x4 sv[2][4] = {};
      __builtin_amdgcn_s_setprio(1);
      #pragma unroll
      for (int kt = 0; kt < 2; kt++){
        bf16x8 kf[4];
        #pragma unroll
        for (int nf = 0; nf < 4; nf++){
          int row = nf*16 + lr;
          int cb  = (kt*64 + lg*16) ^ ((row & 7) << 4);
          kf[nf] = *(const bf16x8*)(kpc + row*128 + cb);
        }
        #pragma unroll
        for (int mf = 0; mf < 2; mf++)
          #pragma unroll
          for (int nf = 0; nf < 4; nf++)
            sv[mf][nf] = MFMA(qf[mf][kt], kf[nf], sv[mf][nf]);
      }
      __builtin_amdgcn_s_setprio(0);
      #pragma unroll
      for (int mf = 0; mf < 2; mf++)
        #pragma unroll
        for (int nfp = 0; nfp < 2; nfp++)
          #pragma unroll
          for (int r = 0; r < 4; r++){
            int nfA = nfp*2, nfB = nfp*2 + 1;
            float xa, xb_;
            if (btab){
              int qw = w*32 + mf*16 + lg*4 + r;
              xa = __builtin_fmaf(sv[mf][nfA][r], SC, btab[(qw << 8) + s*64 + nfA*16 + lr]);
              xb_= __builtin_fmaf(sv[mf][nfB][r], SC, btab[(qw << 8) + s*64 + nfB*16 + lr]);
            } else {
              xa = sv[mf][nfA][r] * SC;
              xb_= sv[mf][nfB][r] * SC;
            }
            unsigned pk = cvt_pk_bf16(fast_exp2(xa), fast_exp2(xb_));
            int row = mf*16 + lg*4 + r;
            int swz = (row & 7) << 4;
            *(unsigned short*)(pw + row*128 + (((nfA*16 + lr)*2) ^ swz)) = (unsigned short)pk;
            *(unsigned short*)(pw + row*128 + (((nfB*16 + lr)*2) ^ swz)) = (unsigned short)(pk >> 16);
          }
      #pragma unroll
      for (int kg = 0; kg < 2; kg++){
        bf16x8 pa[2], vf[4];
        #pragma unroll
        for (int mf = 0; mf < 2; mf++){
          int row = mf*16 + lr;
          int cb  = (kg*64 + lg*16) ^ ((row & 7) << 4);
          pa[mf] = *(const bf16x8*)(pw + row*128 + cb);
        }
        #pragma unroll
        for (int df = 0; df < 4; df++){
          int row = df*16 + lr;
          int cb  = (kg*64 + lg*16) ^ ((row & 7) << 4);
          vf[df] = *(const bf16x8*)(vpc + row*128 + cb);
        }
        __builtin_amdgcn_s_setprio(1);
        #pragma unroll
        for (int mf = 0; mf < 2; mf++){
          #pragma unroll
          for (int df = 0; df < 4; df++)
            ao[mf][df] = MFMA(pa[mf], vf[df], ao[mf][df]);
          lsum4[mf] = MFMA(pa[mf], ones8, lsum4[mf]);
        }
        __builtin_amdgcn_s_setprio(0);
      }
      asm volatile("s_waitcnt vmcnt(0)" ::: "memory");
      __builtin_amdgcn_s_barrier();
    }

    if (h == 0){
      #pragma unroll
      for (int mf = 0; mf < 2; mf++)
        #pragma unroll
        for (int r = 0; r < 4; r++){
          int qt = w*32 + mf*16 + lg*4 + r;
          size_t rowb = (((size_t)(b*2 + chunk)) << 12) + win*256 + qt;
          if (lr == 0) pl[rowb] = lsum4[mf][r];
          #pragma unroll
          for (int df = 0; df < 4; df++)
            pO[(rowb << 6) + df*16 + lr] = f2bf(ao[mf][df][r]);
        }
    } else {
      #pragma unroll
      for (int mf = 0; mf < 2; mf++)
        #pragma unroll
        for (int df = 0; df < 4; df++)
          #pragma unroll
          for (int r = 0; r < 4; r++){
            float o = ao[mf][df][r] / lsum4[mf][r];
            int qt = w*32 + mf*16 + lg*4 + r;
            int np = win*256 + qt;
            fsp[(((size_t)b*4096 + np) << 9) + h*64 + df*16 + lr] = f2bf(o);
          }
    }
  } else {
    int j = u - 64;
    int h = 1 + (j >> 5);
    int jj = j & 31;
    int ui = w >> 2, wi = w & 3;
    int u15 = jj*2 + ui;
    const size_t hb = ((size_t)(b*8 + h)) << 18;
    const float* bt = b64 + ((size_t)(h-1) << 12);
    char* base = (char*)&KV[0][0] + ui*16384;

    #pragma unroll
    for (int i = 0; i < 2; i++){
      int r = wi*16 + i*8 + (l >> 3);
      int sc = (((l & 7) ^ (r & 7)) << 3);
      gload16(kb  + hb + ((size_t)mapw(h, u15, r) << 6) + sc, base + (wi*16 + i*8)*128);
      gload16(vtb + hb + ((size_t)r << 12) + mapw(h, u15, sc), base + 8192 + (wi*16 + i*8)*128);
    }
    bf16x8 qf0, qf1;
    {
      int qt0 = wi*16 + lr;
      int nq = mapw(h, u15, qt0);
      const unsigned short* qp = qb + hb + ((size_t)nq << 6) + lg*8;
      qf0 = *(const bf16x8*)qp;
      qf1 = *(const bf16x8*)(qp + 32);
    }
    asm volatile("s_waitcnt vmcnt(0)" ::: "memory");
    __builtin_amdgcn_s_barrier();

    const char* kpc = base;
    const char* vpc = base + 8192;
    f32x4 ao4[4] = {};
    f32x4 ls = {};

    #pragma unroll
    for (int nfp = 0; nfp < 2; nfp++){
      f32x4 sv[2] = {};
      __builtin_amdgcn_s_setprio(1);
      #pragma unroll
      for (int kt = 0; kt < 2; kt++)
        #pragma unroll
        for (int nfi = 0; nfi < 2; nfi++){
          int row = (nfp*2 + nfi)*16 + lr;
          int cb  = (kt*64 + lg*16) ^ ((row & 7) << 4);
          bf16x8 kf = *(const bf16x8*)(kpc + row*128 + cb);
          sv[nfi] = MFMA(kt == 0 ? qf0 : qf1, kf, sv[nfi]);
        }
      __builtin_amdgcn_s_setprio(0);
      #pragma unroll
      for (int r = 0; r < 4; r++){
        int qw = wi*16 + lg*4 + r;
        float xa = __builtin_fmaf(sv[0][r], SC, bt[(qw << 6) + (nfp*2)*16 + lr]);
        float xb_= __builtin_fmaf(sv[1][r], SC, bt[(qw << 6) + (nfp*2+1)*16 + lr]);
        unsigned pk = cvt_pk_bf16(fast_exp2(xa), fast_exp2(xb_));
        int row = lg*4 + r;
        int swz = (row & 7) << 4;
        *(unsigned short*)(pw + row*128 + ((((nfp*2)*16 + lr)*2) ^ swz)) = (unsigned short)pk;
        *(unsigned short*)(pw + row*128 + ((((nfp*2+1)*16 + lr)*2) ^ swz)) = (unsigned short)(pk >> 16);
      }
    }
    #pragma unroll
    for (int kg = 0; kg < 2; kg++){
      bf16x8 pa;
      {
        int cb = (kg*64 + lg*16) ^ ((lr & 7) << 4);
        pa = *(const bf16x8*)(pw + lr*128 + cb);
      }
      __builtin_amdgcn_s_setprio(1);
      #pragma unroll
      for (int df = 0; df < 4; df++){
        int row = df*16 + lr;
        int cb  = (kg*64 + lg*16) ^ ((row & 7) << 4);
        bf16x8 vf = *(const bf16x8*)(vpc + row*128 + cb);
        ao4[df] = MFMA(pa, vf, ao4[df]);
      }
      ls = MFMA(pa, ones8, ls);
      __builtin_amdgcn_s_setprio(0);
    }
    #pragma unroll
    for (int df = 0; df < 4; df++)
      #pragma unroll
      for (int r = 0; r < 4; r++){
        float o = ao4[df][r] / ls[r];
        int qt = wi*16 + lg*4 + r;
        int np;
        if (h <= 2){
          int r4 = qt >> 4, w_ = (qt >> 2) & 3, c = qt & 3;
          np = (u15 >> 2)*256 + (u15 & 3)*64 + w_*16 + r4*4 + c;
        } else {
          np = u15*64 + qt;
        }
        fsp[(((size_t)b*4096 + np) << 9) + h*64 + df*16 + lr] = f2bf(o);
      }
  }
}

// ---------- combine head-0 KV chunks (2-way sums, vectorized) ----------
__global__ __launch_bounds__(256)
void k_comb(const unsigned short* __restrict__ pO, const float* __restrict__ pl,
            unsigned short* __restrict__ fsp){
  int tid = blockIdx.x*256 + threadIdx.x;      // 512K = 32768 rows * 16 d4-groups
  int d4 = (tid & 15) << 2;
  int row = tid >> 4;
  int b = row >> 12;
  int n = row & 4095;
  size_t r0 = (((size_t)(b*2 + 0)) << 12) + n;
  size_t r1 = (((size_t)(b*2 + 1)) << 12) + n;
  float L = pl[r0] + pl[r1];
  ushort4 a = *(const ushort4*)(pO + (r0 << 6) + d4);
  ushort4 c = *(const ushort4*)(pO + (r1 << 6) + d4);
  ushort4 o;
  o.x = f2bf((bf2f(a.x) + bf2f(c.x)) / L);
  o.y = f2bf((bf2f(a.y) + bf2f(c.y)) / L);
  o.z = f2bf((bf2f(a.z) + bf2f(c.z)) / L);
  o.w = f2bf((bf2f(a.w) + bf2f(c.w)) / L);
  *(ushort4*)(fsp + (((size_t)b*4096 + n) << 9) + d4) = o;
}

// ---------- launch ----------
extern "C" void kernel_launch(void* const* d_in, const int* in_sizes, int n_in,
                              void* d_out, int out_size, void* d_ws, size_t ws_size,
                              hipStream_t stream) {
  const float* x     = (const float*)d_in[0];
  const float* Wq    = (const float*)d_in[1];
  const float* Wkv   = (const float*)d_in[2];
  const float* Wp    = (const float*)d_in[3];
  const float* bproj = (const float*)d_in[4];
  const float* t1 = (const float*)d_in[7];
  const float* t2 = (const float*)d_in[8];
  const float* t3 = (const float*)d_in[9];
  const float* t4 = (const float*)d_in[10];
  const float* t5 = (const float*)d_in[11];
  const float* t6 = (const float*)d_in[12];
  const float* t7 = (const float*)d_in[13];

  char* W = (char*)d_ws;
  size_t off = 0;
  auto alloc = [&](size_t bytes)->char*{
    char* p = W + off; off += (bytes + 255) & ~(size_t)255; return p;
  };
  unsigned short* xb   = (unsigned short*)alloc((size_t)32768*512*2);   // dead after gemm0
  unsigned short* wqkv = (unsigned short*)alloc((size_t)1536*512*2);    // dead after gemm0
  unsigned short* wsp  = (unsigned short*)alloc((size_t)512*512*2);
  unsigned short* qbuf = (unsigned short*)alloc((size_t)8*8*4096*64*2);
  unsigned short* kbuf = (unsigned short*)alloc((size_t)8*8*4096*64*2);
  unsigned short* vtb  = (unsigned short*)alloc((size_t)8*8*4096*64*2);
  unsigned short* fsp  = (unsigned short*)alloc((size_t)32768*512*2);
  float* b64  = (float*)alloc((size_t)5*64*64*4);
  float* b256 = (float*)alloc((size_t)2*256*256*4);
  if (off > ws_size) return;

  unsigned short* pO = xb;                 // 16 chunk-units * 4096 rows * 64 d * 2B = 8 MiB
  float* pl = (float*)wqkv;                // 16*4096*4B = 256 KiB

  k_prep<<<8192, 256, 0, stream>>>(x, xb, Wq, Wkv, Wp, t1,t2,t3,t4,t5,t6,t7,
                                   wqkv, wsp, b64, b256);
  k_gemm<0><<<3072, 256, 0, stream>>>(xb, wqkv, 32768,
                                      qbuf, kbuf, vtb, nullptr, nullptr);
  k_attn<<<1792, 512, 0, stream>>>(qbuf, kbuf, vtb, b64, b256, fsp, pO, pl);
  k_comb<<<2048, 256, 0, stream>>>(pO, pl, fsp);
  k_gemm<1><<<1024, 256, 0, stream>>>(fsp, wsp, 32768,
                                      nullptr, nullptr, nullptr, (float*)d_out, bproj);
}

// Round 21
// 202.165 us; speedup vs baseline: 1.2661x; 1.1707x over previous
//
#include <hip/hip_runtime.h>
#include <stdint.h>

typedef __attribute__((ext_vector_type(8)))  short    bf16x8;
typedef __attribute__((ext_vector_type(4)))  float    f32x4;
typedef __attribute__((ext_vector_type(16))) float    f32x16;
typedef __attribute__((ext_vector_type(4)))  unsigned u32x4;

#define LOG2E 1.4426950408889634f

__device__ __forceinline__ unsigned short f2bf(float f){
  union { float f; unsigned u; } v; v.f = f;
  return (unsigned short)((v.u + 0x7fffu + ((v.u >> 16) & 1u)) >> 16);
}
__device__ __forceinline__ float bf2f(unsigned short h){
  union { unsigned u; float f; } v; v.u = ((unsigned)h) << 16; return v.f;
}
__device__ __forceinline__ float fast_exp2(float x){
  float r; asm("v_exp_f32 %0, %1" : "=v"(r) : "v"(x)); return r;
}
__device__ __forceinline__ unsigned cvt_pk_bf16(float lo, float hi){
  unsigned r; asm("v_cvt_pk_bf16_f32 %0, %1, %2" : "=v"(r) : "v"(lo), "v"(hi)); return r;
}
__device__ __forceinline__ void plane_swap(unsigned &x, unsigned &y){
  asm volatile("v_permlane32_swap_b32 %0, %1" : "+v"(x), "+v"(y));
}
__device__ __forceinline__ void gload16(const void* g, void* lds){
  __builtin_amdgcn_global_load_lds((const __attribute__((address_space(1))) unsigned int*)g,
                                   (__attribute__((address_space(3))) unsigned int*)lds,
                                   16, 0, 0);
}
#define MFMA(a,b,c)   __builtin_amdgcn_mfma_f32_16x16x32_bf16((a),(b),(c),0,0,0)
#define MFMA32(a,b,c) __builtin_amdgcn_mfma_f32_32x32x16_bf16((a),(b),(c),0,0,0)

// B=8, H=W=64, N=4096, C=512, nh=8, hd=64

// Merged prep: x->bf16 + weights + bias tables (pre-scaled by log2(e)).
__global__ __launch_bounds__(256)
void k_prep(const float* __restrict__ x, unsigned short* __restrict__ xb,
            const float* __restrict__ Wq, const float* __restrict__ Wkv,
            const float* __restrict__ Wp,
            const float* t1,const float* t2,const float* t3,const float* t4,
            const float* t5,const float* t6,const float* t7,
            unsigned short* __restrict__ wqkv, unsigned short* __restrict__ wsp,
            float* __restrict__ b64, float* __restrict__ b256){
  int gid = blockIdx.x*256 + threadIdx.x;
  int stride = gridDim.x*256;
  int i8 = gid*8;
  if (i8 < 32768*512){
    float4 a = *(const float4*)(x+i8);
    float4 bb = *(const float4*)(x+i8+4);
    *(ushort4*)(xb+i8)   = make_ushort4(f2bf(a.x), f2bf(a.y), f2bf(a.z), f2bf(a.w));
    *(ushort4*)(xb+i8+4) = make_ushort4(f2bf(bb.x), f2bf(bb.y), f2bf(bb.z), f2bf(bb.w));
  }
  for (int e = gid; e < 1536*512; e += stride){
    int r = e >> 9;
    wqkv[e] = f2bf(r < 512 ? Wq[e] : Wkv[e - 512*512]);
  }
  for (int e = gid; e < 512*512; e += stride)
    wsp[e] = f2bf(Wp[e]);
  for (int e = gid; e < 5*4096; e += stride){
    int hh = e >> 12;
    int q = (e >> 6) & 63, kk = e & 63;
    float v;
    if (hh < 2){
      const float* tb = hh ? t2 : t1;
      int r1=q>>4, i1=(q>>2)&3, c1=q&3;
      int r2=kk>>4, i2=(kk>>2)&3, c2=kk&3;
      v = (i1==i2) ? tb[(r1-r2+3)*7 + (c1-c2+3)] : -1e30f;
    } else {
      const float* tb = (hh==2)?t3:((hh==3)?t4:t5);
      int r1=q>>3, c1=q&7, r2=kk>>3, c2=kk&7;
      v = tb[(r1-r2+7)*15 + (c1-c2+7)];
    }
    b64[e] = v * LOG2E;
  }
  for (int e = gid; e < 2*65536; e += stride){
    int hh = e >> 16; int q = (e >> 8) & 255, kk = e & 255;
    const float* tb = hh ? t7 : t6;
    int r1=q>>4, c1=q&15, r2=kk>>4, c2=kk&15;
    b256[e] = tb[(r1-r2+15)*31 + (c1-c2+15)] * LOG2E;
  }
}

// ---------- GEMM (validated machinery), A-panel-major XCD-chunked block mapping ----------
template<int EPI>
__global__ __launch_bounds__(256, 2)
void k_gemm(const unsigned short* __restrict__ A, const unsigned short* __restrict__ Bw,
            int M,
            unsigned short* __restrict__ oq, unsigned short* __restrict__ ok,
            unsigned short* __restrict__ ovt,
            float* __restrict__ of, const float* __restrict__ bias)
{
  __shared__ unsigned short As[128*64];
  __shared__ unsigned short Bs[128*64];
  const int t = threadIdx.x, l = t & 63, w = t >> 6;
  const int mt = M >> 7;
  const int nt = (EPI == 0) ? 12 : 4;
  const int xcd = blockIdx.x & 7;
  const int idx = blockIdx.x >> 3;
  const int bm = xcd*(mt >> 3) + idx / nt;
  const int bn = idx % nt;
  const int m0 = bm << 7, n0 = bn << 7;
  const int wr = w >> 1, wc = w & 1;
  const int lr = l & 15, lg = l >> 4;
  f32x4 acc[4][4] = {};

  for (int k0 = 0; k0 < 512; k0 += 64){
    #pragma unroll
    for (int i = 0; i < 4; i++){
      int rowb = i*32 + w*8;
      int row  = rowb + (l >> 3);
      int sc   = (((l & 7) ^ (row & 7)) << 3);
      gload16(A  + (size_t)(m0 + row)*512 + k0 + sc, &As[rowb*64]);
      gload16(Bw + (size_t)(n0 + row)*512 + k0 + sc, &Bs[rowb*64]);
    }
    __syncthreads();
    #pragma unroll
    for (int kt = 0; kt < 2; kt++){
      bf16x8 af[4], bfr[4];
      #pragma unroll
      for (int mi = 0; mi < 4; mi++){
        int row = wr*64 + mi*16 + lr;
        int cb  = (kt*64 + lg*16) ^ ((row & 7) << 4);
        af[mi] = *(const bf16x8*)((const char*)As + row*128 + cb);
      }
      #pragma unroll
      for (int ni = 0; ni < 4; ni++){
        int row = wc*64 + ni*16 + lr;
        int cb  = (kt*64 + lg*16) ^ ((row & 7) << 4);
        bfr[ni] = *(const bf16x8*)((const char*)Bs + row*128 + cb);
      }
      #pragma unroll
      for (int mi = 0; mi < 4; mi++)
        #pragma unroll
        for (int ni = 0; ni < 4; ni++)
          acc[mi][ni] = MFMA(af[mi], bfr[ni], acc[mi][ni]);
    }
    __syncthreads();
  }

  #pragma unroll
  for (int mi = 0; mi < 4; mi++){
    #pragma unroll
    for (int ni = 0; ni < 4; ni++){
      int m = m0 + wr*64 + mi*16 + lg*4;
      int o = n0 + wc*64 + ni*16 + lr;
      if (EPI == 0){
        int which = o >> 9, oo = o & 511, h = oo >> 6, d = oo & 63;
        int b_ = m >> 12, n_ = m & 4095;
        if (which == 2){
          *(ushort4*)(ovt + ((((size_t)b_*8 + h)*64 + d) << 12) + n_) =
            make_ushort4(f2bf(acc[mi][ni][0]), f2bf(acc[mi][ni][1]),
                         f2bf(acc[mi][ni][2]), f2bf(acc[mi][ni][3]));
        } else {
          unsigned short* dst = (which == 0) ? oq : ok;
          size_t base = (((size_t)(b_*8 + h)) << 18) + ((size_t)n_ << 6) + d;
          #pragma unroll
          for (int r = 0; r < 4; r++)
            dst[base + (size_t)r*64] = f2bf(acc[mi][ni][r]);
        }
      } else {
        float bv = bias[o];
        #pragma unroll
        for (int r = 0; r < 4; r++)
          of[(size_t)(m + r)*512 + o] = acc[mi][ni][r] + bv;
      }
    }
  }
}

// ---------- unified attention: h0/h67 on swapped-QK 32x32 (no P LDS roundtrip) ----------
__device__ __forceinline__ int map16(int win, int t){
  return (((win >> 2)*16 + (t >> 4)) << 6) + ((win & 3) << 4) + (t & 15);
}
__device__ __forceinline__ int mapw(int h, int u, int t){
  if (h <= 2) return (((u >> 2)*4 + (t >> 4)) << 6) + ((u & 3) << 4) + (t & 15);
  return (((u >> 3)*8 + (t >> 3)) << 6) + ((u & 7) << 3) + (t & 7);
}

__global__ __launch_bounds__(512)
void k_attn(const unsigned short* __restrict__ qb, const unsigned short* __restrict__ kb,
            const unsigned short* __restrict__ vtb,
            const float* __restrict__ b64, const float* __restrict__ b256,
            unsigned short* __restrict__ fsp,
            unsigned short* __restrict__ pO, float* __restrict__ pl)
{
  __shared__ unsigned short KV[2][8192];           // h0/h67: dbuf [K|V]; h15: 2 units
  __shared__ unsigned short Pp[8][2048];           // h15 P only
  const int t = threadIdx.x, l = t & 63, w = t >> 6;
  const int lr = l & 15, lg = l >> 4;
  const int v = (blockIdx.x & 7)*224 + (blockIdx.x >> 3);   // XCD-pinned, 1792 blocks
  const int b = v / 224, u = v % 224;
  const float SC = 0.125f * LOG2E;
  char* pw = (char*)Pp[w];
  bf16x8 ones8;
  #pragma unroll
  for (int e = 0; e < 8; e++) ones8[e] = (short)0x3F80;

  if (u < 64){
    // ======== h0 (2-way KV-chunked) and h6/7, swapped-QK 32x32 path ========
    int h, win, s0, s1, chunk = 0, u0;
    const float* btab = nullptr;
    if (u < 32){ h = 0; win = u >> 1; chunk = u & 1; s0 = chunk*32; s1 = s0 + 32;
                 u0 = b*2 + chunk; }
    else { int uu = u - 32; h = 6 + (uu >> 4); win = uu & 15; s0 = 0; s1 = 4;
           btab = b256 + ((size_t)(h - 6) << 16);
           u0 = 16 + b*2 + (h - 6); }
    const size_t hb = ((size_t)(b*8 + h)) << 18;
    const int l31 = l & 31, hi = l >> 5;

    const int srow = w*8 + (l >> 3);
    const int ssc  = (((l & 7) ^ (srow & 7)) << 3);

    // Q fragments: B-operand of 32x32x16, q = w*32 + l31, d-chunk dc*16 + hi*8
    bf16x8 qf[4];
    {
      int qt = w*32 + l31;
      int n = (h == 0) ? (win*256 + qt) : map16(win, qt);
      const unsigned short* qp = qb + hb + ((size_t)n << 6) + hi*8;
      #pragma unroll
      for (int dc = 0; dc < 4; dc++)
        qf[dc] = *(const bf16x8*)(qp + dc*16);
    }
    f32x16 ao2[2] = {};
    float lsum = 0.f;

    auto stage = [&](int s, int buf){
      int tk = s*64 + srow;
      int nk = (h == 0) ? tk : map16(win, tk);
      gload16(kb + hb + ((size_t)nk << 6) + ssc, &KV[buf][w*512]);
      int tv = s*64 + ssc;
      int nv = (h == 0) ? tv : map16(win, tv);
      gload16(vtb + hb + ((size_t)srow << 12) + nv, &KV[buf][4096 + w*512]);
    };

    stage(s0, 0);
    asm volatile("s_waitcnt vmcnt(0)" ::: "memory");
    __builtin_amdgcn_s_barrier();

    for (int s = s0; s < s1; s++){
      const int cur = (s - s0) & 1;
      if (s + 1 < s1) stage(s + 1, cur ^ 1);
      const char* kpc = (const char*)&KV[cur][0];
      const char* vpc = (const char*)&KV[cur][4096];

      u32x4 pa4[4];
      #pragma unroll
      for (int kt = 0; kt < 2; kt++){
        // QK^T swapped: D[key][query], A = K tile rows kt*32+l31
        f32x16 sv = {};
        __builtin_amdgcn_s_setprio(1);
        #pragma unroll
        for (int dc = 0; dc < 4; dc++){
          int row = kt*32 + l31;
          int cb  = (dc*32 + hi*16) ^ ((row & 7) << 4);
          bf16x8 kv = *(const bf16x8*)(kpc + row*128 + cb);
          sv = MFMA32(kv, qf[dc], sv);
        }
        __builtin_amdgcn_s_setprio(0);
        // softmax (base-2, no shift); key(reg) = (r&3)+8*(r>>2)+4*hi within tile
        float p[16];
        #pragma unroll
        for (int r = 0; r < 16; r++){
          float x;
          if (btab){
            int qw = w*32 + l31;
            int kw = s*64 + kt*32 + (r & 3) + 8*(r >> 2) + 4*hi;
            x = __builtin_fmaf(sv[r], SC, btab[(qw << 8) + kw]);
          } else {
            x = sv[r] * SC;
          }
          p[r] = fast_exp2(x);
          lsum += p[r];
        }
        // pack + permlane32_swap -> PA fragments (keys hi*8..+8 per 16-key slot)
        #pragma unroll
        for (int sub = 0; sub < 2; sub++){
          int r0 = sub*8;
          unsigned x1 = cvt_pk_bf16(p[r0+0], p[r0+1]);
          unsigned x2 = cvt_pk_bf16(p[r0+2], p[r0+3]);
          unsigned y1 = cvt_pk_bf16(p[r0+4], p[r0+5]);
          unsigned y2 = cvt_pk_bf16(p[r0+6], p[r0+7]);
          plane_swap(x1, y1);
          plane_swap(x2, y2);
          pa4[kt*2 + sub] = (u32x4){x1, x2, y1, y2};
        }
      }
      // PV: O[q][d] += P.V  (A = PA, B = V^T tile rows dt*32+l31)
      __builtin_amdgcn_s_setprio(1);
      #pragma unroll
      for (int ks = 0; ks < 4; ks++){
        bf16x8 paf = __builtin_bit_cast(bf16x8, pa4[ks]);
        #pragma unroll
        for (int dt = 0; dt < 2; dt++){
          int row = dt*32 + l31;
          int cb  = (ks*32 + hi*16) ^ ((row & 7) << 4);
          bf16x8 vv = *(const bf16x8*)(vpc + row*128 + cb);
          ao2[dt] = MFMA32(paf, vv, ao2[dt]);
        }
      }
      __builtin_amdgcn_s_setprio(0);
      asm volatile("s_waitcnt vmcnt(0)" ::: "memory");
      __builtin_amdgcn_s_barrier();
    }

    // epilogue: unnormalized partials for BOTH h0 and h67 (comb divides)
    float lt = lsum + __shfl_xor(lsum, 32);
    int qbase = win*256 + w*32;
    if (l < 32) pl[((size_t)u0 << 12) + qbase + l31] = lt;
    #pragma unroll
    for (int dt = 0; dt < 2; dt++)
      #pragma unroll
      for (int r = 0; r < 16; r++){
        int q = qbase + (r & 3) + 8*(r >> 2) + 4*hi;
        int d = dt*32 + l31;
        pO[((((size_t)u0 << 12) + q) << 6) + d] = f2bf(ao2[dt][r]);
      }
  } else {
    // ================= h1..5: unchanged validated 16x16 path =================
    int j = u - 64;
    int h = 1 + (j >> 5);
    int jj = j & 31;
    int ui = w >> 2, wi = w & 3;
    int u15 = jj*2 + ui;
    const size_t hb = ((size_t)(b*8 + h)) << 18;
    const float* bt = b64 + ((size_t)(h-1) << 12);
    char* base = (char*)&KV[0][0] + ui*16384;

    #pragma unroll
    for (int i = 0; i < 2; i++){
      int r = wi*16 + i*8 + (l >> 3);
      int sc = (((l & 7) ^ (r & 7)) << 3);
      gload16(kb  + hb + ((size_t)mapw(h, u15, r) << 6) + sc, base + (wi*16 + i*8)*128);
      gload16(vtb + hb + ((size_t)r << 12) + mapw(h, u15, sc), base + 8192 + (wi*16 + i*8)*128);
    }
    bf16x8 qf0, qf1;
    {
      int qt0 = wi*16 + lr;
      int nq = mapw(h, u15, qt0);
      const unsigned short* qp = qb + hb + ((size_t)nq << 6) + lg*8;
      qf0 = *(const bf16x8*)qp;
      qf1 = *(const bf16x8*)(qp + 32);
    }
    asm volatile("s_waitcnt vmcnt(0)" ::: "memory");
    __builtin_amdgcn_s_barrier();

    const char* kpc = base;
    const char* vpc = base + 8192;
    f32x4 ao4[4] = {};
    f32x4 ls = {};

    #pragma unroll
    for (int nfp = 0; nfp < 2; nfp++){
      f32x4 sv[2] = {};
      __builtin_amdgcn_s_setprio(1);
      #pragma unroll
      for (int kt = 0; kt < 2; kt++)
        #pragma unroll
        for (int nfi = 0; nfi < 2; nfi++){
          int row = (nfp*2 + nfi)*16 + lr;
          int cb  = (kt*64 + lg*16) ^ ((row & 7) << 4);
          bf16x8 kf = *(const bf16x8*)(kpc + row*128 + cb);
          sv[nfi] = MFMA(kt == 0 ? qf0 : qf1, kf, sv[nfi]);
        }
      __builtin_amdgcn_s_setprio(0);
      #pragma unroll
      for (int r = 0; r < 4; r++){
        int qw = wi*16 + lg*4 + r;
        float xa = __builtin_fmaf(sv[0][r], SC, bt[(qw << 6) + (nfp*2)*16 + lr]);
        float xb_= __builtin_fmaf(sv[1][r], SC, bt[(qw << 6) + (nfp*2+1)*16 + lr]);
        unsigned pk = cvt_pk_bf16(fast_exp2(xa), fast_exp2(xb_));
        int row = lg*4 + r;
        int swz = (row & 7) << 4;
        *(unsigned short*)(pw + row*128 + ((((nfp*2)*16 + lr)*2) ^ swz)) = (unsigned short)pk;
        *(unsigned short*)(pw + row*128 + ((((nfp*2+1)*16 + lr)*2) ^ swz)) = (unsigned short)(pk >> 16);
      }
    }
    #pragma unroll
    for (int kg = 0; kg < 2; kg++){
      bf16x8 pa;
      {
        int cb = (kg*64 + lg*16) ^ ((lr & 7) << 4);
        pa = *(const bf16x8*)(pw + lr*128 + cb);
      }
      __builtin_amdgcn_s_setprio(1);
      #pragma unroll
      for (int df = 0; df < 4; df++){
        int row = df*16 + lr;
        int cb  = (kg*64 + lg*16) ^ ((row & 7) << 4);
        bf16x8 vf = *(const bf16x8*)(vpc + row*128 + cb);
        ao4[df] = MFMA(pa, vf, ao4[df]);
      }
      ls = MFMA(pa, ones8, ls);
      __builtin_amdgcn_s_setprio(0);
    }
    #pragma unroll
    for (int df = 0; df < 4; df++)
      #pragma unroll
      for (int r = 0; r < 4; r++){
        float o = ao4[df][r] / ls[r];
        int qt = wi*16 + lg*4 + r;
        int np;
        if (h <= 2){
          int r4 = qt >> 4, w_ = (qt >> 2) & 3, c = qt & 3;
          np = (u15 >> 2)*256 + (u15 & 3)*64 + w_*16 + r4*4 + c;
        } else {
          np = u15*64 + qt;
        }
        fsp[(((size_t)b*4096 + np) << 9) + h*64 + df*16 + lr] = f2bf(o);
      }
  }
}

// ---------- combine: h0 (sum 2 chunks, divide), h67 (divide), vectorized ----------
__global__ __launch_bounds__(256)
void k_comb(const unsigned short* __restrict__ pO, const float* __restrict__ pl,
            unsigned short* __restrict__ fsp){
  int tid = blockIdx.x*256 + threadIdx.x;      // 98304 rows * 16 d4-groups
  int d4 = (tid & 15) << 2;
  int row = tid >> 4;
  float L, o0, o1, o2, o3;
  size_t outb;
  if (row < 32768){
    int b = row >> 12, n = row & 4095;
    size_t r0 = (((size_t)(b*2 + 0)) << 12) + n;
    size_t r1 = (((size_t)(b*2 + 1)) << 12) + n;
    L = pl[r0] + pl[r1];
    ushort4 a = *(const ushort4*)(pO + (r0 << 6) + d4);
    ushort4 c = *(const ushort4*)(pO + (r1 << 6) + d4);
    o0 = bf2f(a.x)+bf2f(c.x); o1 = bf2f(a.y)+bf2f(c.y);
    o2 = bf2f(a.z)+bf2f(c.z); o3 = bf2f(a.w)+bf2f(c.w);
    outb = (((size_t)b*4096 + n) << 9) + d4;
  } else {
    int rr = row - 32768;
    int b = rr >> 13, rem = rr & 8191, hh = rem >> 12, n = rem & 4095;
    size_t r0 = (((size_t)(16 + b*2 + hh)) << 12) + n;
    L = pl[r0];
    ushort4 a = *(const ushort4*)(pO + (r0 << 6) + d4);
    o0 = bf2f(a.x); o1 = bf2f(a.y); o2 = bf2f(a.z); o3 = bf2f(a.w);
    outb = (((size_t)b*4096 + n) << 9) + (6 + hh)*64 + d4;
  }
  ushort4 ov;
  ov.x = f2bf(o0 / L); ov.y = f2bf(o1 / L);
  ov.z = f2bf(o2 / L); ov.w = f2bf(o3 / L);
  *(ushort4*)(fsp + outb) = ov;
}

// ---------- launch ----------
extern "C" void kernel_launch(void* const* d_in, const int* in_sizes, int n_in,
                              void* d_out, int out_size, void* d_ws, size_t ws_size,
                              hipStream_t stream) {
  const float* x     = (const float*)d_in[0];
  const float* Wq    = (const float*)d_in[1];
  const float* Wkv   = (const float*)d_in[2];
  const float* Wp    = (const float*)d_in[3];
  const float* bproj = (const float*)d_in[4];
  const float* t1 = (const float*)d_in[7];
  const float* t2 = (const float*)d_in[8];
  const float* t3 = (const float*)d_in[9];
  const float* t4 = (const float*)d_in[10];
  const float* t5 = (const float*)d_in[11];
  const float* t6 = (const float*)d_in[12];
  const float* t7 = (const float*)d_in[13];

  char* W = (char*)d_ws;
  size_t off = 0;
  auto alloc = [&](size_t bytes)->char*{
    char* p = W + off; off += (bytes + 255) & ~(size_t)255; return p;
  };
  unsigned short* xb   = (unsigned short*)alloc((size_t)32768*512*2);   // dead after gemm0
  unsigned short* wqkv = (unsigned short*)alloc((size_t)1536*512*2);    // dead after gemm0
  unsigned short* wsp  = (unsigned short*)alloc((size_t)512*512*2);
  unsigned short* qbuf = (unsigned short*)alloc((size_t)8*8*4096*64*2);
  unsigned short* kbuf = (unsigned short*)alloc((size_t)8*8*4096*64*2);
  unsigned short* vtb  = (unsigned short*)alloc((size_t)8*8*4096*64*2);
  unsigned short* fsp  = (unsigned short*)alloc((size_t)32768*512*2);
  float* b64  = (float*)alloc((size_t)5*64*64*4);
  float* b256 = (float*)alloc((size_t)2*256*256*4);
  if (off > ws_size) return;

  unsigned short* pO = xb;                 // 32 units * 4096 rows * 64 d * 2B = 16 MiB
  float* pl = (float*)wqkv;                // 32*4096*4B = 512 KiB

  k_prep<<<8192, 256, 0, stream>>>(x, xb, Wq, Wkv, Wp, t1,t2,t3,t4,t5,t6,t7,
                                   wqkv, wsp, b64, b256);
  k_gemm<0><<<3072, 256, 0, stream>>>(xb, wqkv, 32768,
                                      qbuf, kbuf, vtb, nullptr, nullptr);
  k_attn<<<1792, 512, 0, stream>>>(qbuf, kbuf, vtb, b64, b256, fsp, pO, pl);
  k_comb<<<6144, 256, 0, stream>>>(pO, pl, fsp);
  k_gemm<1><<<1024, 256, 0, stream>>>(fsp, wsp, 32768,
                                      nullptr, nullptr, nullptr, (float*)d_out, bproj);
}